// Round 11
// baseline (531.215 us; speedup 1.0000x reference)
//
#include <hip/hip_runtime.h>
#include <math.h>

#define BB 32
#define SE 149
#define SP 99
#define LE_LEN 3000
#define LP_LEN 2000
#define VT 8
#define ROWS_EN (BB * SE)              // 4768
#define ROWS_PR (BB * SP)              // 3168
#define ROWS_ALL (ROWS_EN + ROWS_PR)   // 7936
#define ROWS_EXT (ROWS_ALL + ROWS_PR)  // 11104 (extra region for self-pr)

__device__ __forceinline__ void row_decode(int row, int& branch, int& b,
                                           int& s, int& S, int& lrow) {
  if (row < ROWS_EN) { branch = 0; S = SE; lrow = row; b = row / SE; s = row - b * SE; }
  else { branch = 1; S = SP; lrow = row - ROWS_EN; b = lrow / SP; s = lrow - b * SP; }
}

// ---------- prep: conv_w transposes (en+pr), proj transposes, Al zero ----------
__global__ __launch_bounds__(256) void prep_kernel(
    const float* __restrict__ cw_en, const float* __restrict__ cw_pr,
    const float* __restrict__ cross_in, const float* __restrict__ cross_out,
    const float* __restrict__ self_in, const float* __restrict__ self_out,
    float* __restrict__ W2en, float* __restrict__ W2pr,
    float* __restrict__ Wt, float* __restrict__ Al) {
  int bb = blockIdx.x;
  if (bb == 0 && threadIdx.x == 0) Al[0] = 0.f;
  if (bb < 576) {
    const float* src = (bb < 288) ? cw_en : cw_pr;
    float* dst = (bb < 288) ? W2en : W2pr;
    int i = ((bb < 288) ? bb : bb - 288) * 256 + threadIdx.x;
    int oc = i / 1152, r = i % 1152, ic = r / 9, k = r % 9;
    dst[ic * 576 + k * 64 + oc] = src[i];
  } else {
    int m = bb - 576;  // 0..7
    const float* src = (m < 3) ? cross_in + m * 4096
                     : (m == 3) ? cross_out
                     : (m < 7) ? self_in + (m - 4) * 4096
                     : self_out;
    for (int i = threadIdx.x; i < 4096; i += 256) {
      int o = i >> 6, c = i & 63;
      Wt[m * 4096 + c * 64 + o] = src[i];
    }
  }
}

// ---------- conv table, both branches in one launch ----------
__global__ __launch_bounds__(192) void conv_table_kernel(
    const float* __restrict__ emb_en, const float* __restrict__ emb_pr,
    const float* __restrict__ W2en, const float* __restrict__ W2pr,
    float* __restrict__ Cen, float* __restrict__ Cpr) {
  int blk = blockIdx.x;
  int branch = (blk >= 513);
  const float* emb = branch ? emb_pr : emb_en;
  const float* W2 = branch ? W2pr : W2en;
  float* C = branch ? Cpr : Cen;
  int v0 = (branch ? blk - 513 : blk) * VT;
  __shared__ float e[VT][128];
  int t = threadIdx.x;
  int nv = 4097 - v0; if (nv > VT) nv = VT;
  for (int i = t; i < nv * 128; i += 192) e[i >> 7][i & 127] = emb[v0 * 128 + i];
  __syncthreads();
  float a0[VT], a1[VT], a2[VT];
#pragma unroll
  for (int v = 0; v < VT; ++v) { a0[v] = 0.f; a1[v] = 0.f; a2[v] = 0.f; }
  for (int ic = 0; ic < 128; ++ic) {
    float w0 = W2[ic * 576 + t];
    float w1 = W2[ic * 576 + t + 192];
    float w2 = W2[ic * 576 + t + 384];
#pragma unroll
    for (int v = 0; v < VT; ++v) {
      float ev = e[v][ic];
      a0[v] += ev * w0; a1[v] += ev * w1; a2[v] += ev * w2;
    }
  }
  for (int v = 0; v < nv; ++v) {
    C[(size_t)(v0 + v) * 576 + t] = a0[v];
    C[(size_t)(v0 + v) * 576 + t + 192] = a1[v];
    C[(size_t)(v0 + v) * 576 + t + 384] = a2[v];
  }
}

// ---------- frontend + qkv(l=0) + rope, 4 rows/block ----------
__global__ __launch_bounds__(256) void frontqkv_kernel(
    const int* __restrict__ en_ids, const int* __restrict__ pr_ids,
    const float* __restrict__ Cen, const float* __restrict__ Cpr,
    const float* __restrict__ cb_en, const float* __restrict__ cb_pr,
    const float* __restrict__ bn_en, const float* __restrict__ bn_pr,
    const float* __restrict__ t_qkv_w, const float* __restrict__ t_qkv_b,
    float* __restrict__ Xen, float* __restrict__ Xpr,
    float* __restrict__ Q, float* __restrict__ K, float* __restrict__ V) {
  int t = threadIdx.x;
  int wid = t >> 6, oc = t & 63;
  int row = blockIdx.x * 4 + wid;
  int branch, b, s, S, lrow;
  row_decode(row, branch, b, s, S, lrow);
  const int* ids = branch ? pr_ids : en_ids;
  int Lin = branch ? LP_LEN : LE_LEN;
  const float* C = branch ? Cpr : Cen;
  const float* cb = branch ? cb_pr : cb_en;
  const float* bn = branch ? bn_pr : bn_en;
  float* X = branch ? Xpr : Xen;
  __shared__ int idl[4][28];
  __shared__ float xr[4][64], qs[4][64], ks[4][64];
  if (oc < 28) idl[wid][oc] = ids[b * Lin + s * 20 + oc];
  __syncthreads();
  float bias = cb[oc];
  float m = -INFINITY;
  for (int p = 0; p < 20; ++p) {
    float acc = bias;
#pragma unroll
    for (int k = 0; k < 9; ++k) acc += C[idl[wid][p + k] * 576 + k * 64 + oc];
    acc = fmaxf(acc, 0.f);
    m = fmaxf(m, acc);
  }
  float g = bn[oc], be = bn[64 + oc], mu = bn[128 + oc], var = bn[192 + oc];
  float xv = (m - mu) * rsqrtf(var + 1e-5f) * g + be;
  X[(size_t)lrow * 64 + oc] = xv;
  xr[wid][oc] = xv;
  __syncthreads();
  // qkv for layer 0
  int idx = branch * 2;
  const float* W = t_qkv_w + (size_t)idx * 3 * 4096;
  const float* qb_ = t_qkv_b + idx * 192;
  float q = qb_[oc], k = qb_[64 + oc], v = qb_[128 + oc];
  for (int c = 0; c < 64; ++c) {
    float xc = xr[wid][c];
    q += xc * W[c * 64 + oc];
    k += xc * W[4096 + c * 64 + oc];
    v += xc * W[8192 + c * 64 + oc];
  }
  qs[wid][oc] = q; ks[wid][oc] = k;
  V[row * 64 + oc] = v;
  __syncthreads();
  int j = oc & 7;
  int p = j >> 1;
  float inv = powf(10000.f, -(float)p * 0.25f);
  float ang = (float)s * inv;
  float cc = cosf(ang), ss = sinf(ang);
  float qo, ko;
  if ((j & 1) == 0) {
    qo = qs[wid][oc] * cc - qs[wid][oc + 1] * ss;
    ko = ks[wid][oc] * cc - ks[wid][oc + 1] * ss;
  } else {
    qo = qs[wid][oc - 1] * ss + qs[wid][oc] * cc;
    ko = ks[wid][oc - 1] * ss + ks[wid][oc] * cc;
  }
  Q[row * 64 + oc] = qo;
  K[row * 64 + oc] = ko;
}

// ---------- attention, two sections per launch ----------
__global__ __launch_bounds__(256) void attn_kernel(
    const float* __restrict__ Q, const float* __restrict__ K,
    const float* __restrict__ V, float* __restrict__ ctx,
    int nblk0, int Sq0, int Sk0, int qb0, int kb0, float als0,
    int Sq1, int Sk1, int qb1, int kb1, float als1,
    float* __restrict__ aloss_acc) {
  int blk = blockIdx.x;
  int bh, Sq, Sk, qb, kb; float als;
  if (blk < nblk0) { bh = blk; Sq = Sq0; Sk = Sk0; qb = qb0; kb = kb0; als = als0; }
  else { bh = blk - nblk0; Sq = Sq1; Sk = Sk1; qb = qb1; kb = kb1; als = als1; }
  int b = bh >> 3, h = bh & 7;
  __shared__ float kk[160 * 8], vv[160 * 8];
  int t = threadIdx.x;
  for (int i = t; i < Sk * 8; i += 256) {
    int r = i >> 3, j = i & 7;
    kk[i] = K[(kb + b * Sk + r) * 64 + h * 8 + j];
    vv[i] = V[(kb + b * Sk + r) * 64 + h * 8 + j];
  }
  __syncthreads();
  float rowsum2 = 0.f;
  if (t < Sq) {
    float q[8];
#pragma unroll
    for (int j = 0; j < 8; ++j) q[j] = Q[(qb + b * Sq + t) * 64 + h * 8 + j];
    float m = -INFINITY, sum = 0.f, sum2 = 0.f, acc[8];
#pragma unroll
    for (int j = 0; j < 8; ++j) acc[j] = 0.f;
    const float sc = 0.35355339059327373f;
    for (int kki = 0; kki < Sk; ++kki) {
      float sdot = 0.f;
#pragma unroll
      for (int j = 0; j < 8; ++j) sdot += q[j] * kk[kki * 8 + j];
      sdot *= sc;
      if (sdot > m) {
        float f = expf(m - sdot);
        sum *= f; sum2 *= f * f;
#pragma unroll
        for (int j = 0; j < 8; ++j) acc[j] *= f;
        m = sdot;
      }
      float e = expf(sdot - m);
      sum += e; sum2 += e * e;
#pragma unroll
      for (int j = 0; j < 8; ++j) acc[j] += e * vv[kki * 8 + j];
    }
    float invs = 1.f / sum;
#pragma unroll
    for (int j = 0; j < 8; ++j)
      ctx[(qb + b * Sq + t) * 64 + h * 8 + j] = acc[j] * invs;
    rowsum2 = sum2 * invs * invs;
  }
  if (als != 0.f) {
    float wsum = rowsum2;
    for (int off = 32; off; off >>= 1) wsum += __shfl_down(wsum, off, 64);
    __shared__ float wred[4];
    if ((t & 63) == 0) wred[t >> 6] = wsum;
    __syncthreads();
    if (t == 0) {
      float tot = wred[0] + wred[1] + wred[2] + wred[3];
      atomicAdd(aloss_acc, tot * als);
    }
  }
}

// ---------- fused channel attention + apply + spatial feat (grid 64 × 512) ----------
__global__ __launch_bounds__(512) void cafeat_kernel(
    float* __restrict__ ctx, const float* __restrict__ t_ca_w1,
    const float* __restrict__ t_ca_w2, int l,
    float* __restrict__ fmean, float* __restrict__ fmax) {
  int bp = blockIdx.x;  // 0..63
  int branch = bp >> 5, b = bp & 31;
  int S = branch ? SP : SE;
  int base = branch ? ROWS_EN : 0;
  int idx = branch * 2 + l;
  const float* W1 = t_ca_w1 + idx * 512;
  const float* W2 = t_ca_w2 + idx * 512;
  int t = threadIdx.x;  // 512
  int c = t & 63, seg = t >> 6;  // 8 segments (each seg = one wave)
  float sum = 0.f, mx = -INFINITY;
  for (int s = seg; s < S; s += 8) {
    float v = ctx[(size_t)(base + b * S + s) * 64 + c];
    sum += v; mx = fmaxf(mx, v);
  }
  __shared__ float ssum[8][64], smx[8][64];
  ssum[seg][c] = sum; smx[seg][c] = mx;
  __syncthreads();
  __shared__ float avg_l[64], mx_l[64], ha[8], hm[8], ca_s[64];
  if (t < 64) {
    float a = 0.f, m = -INFINITY;
#pragma unroll
    for (int g = 0; g < 8; ++g) { a += ssum[g][t]; m = fmaxf(m, smx[g][t]); }
    avg_l[t] = a / (float)S; mx_l[t] = m;
  }
  __syncthreads();
  if (t < 8) {
    float a = 0.f, m2 = 0.f;
    for (int i = 0; i < 64; ++i) {
      a += avg_l[i] * W1[i * 8 + t];
      m2 += mx_l[i] * W1[i * 8 + t];
    }
    ha[t] = fmaxf(a, 0.f); hm[t] = fmaxf(m2, 0.f);
  }
  __syncthreads();
  if (t < 64) {
    float o = 0.f;
#pragma unroll
    for (int j = 0; j < 8; ++j) o += (ha[j] + hm[j]) * W2[j * 64 + t];
    ca_s[t] = 1.f / (1.f + expf(-o));
  }
  __syncthreads();
  float cav = ca_s[c];
  for (int s = seg; s < S; s += 8) {
    int grow = base + b * S + s;
    float v = ctx[(size_t)grow * 64 + c] * cav;
    ctx[(size_t)grow * 64 + c] = v;
    float su = v, mv = v;
    for (int off = 32; off; off >>= 1) {
      su += __shfl_xor(su, off, 64);
      mv = fmaxf(mv, __shfl_xor(mv, off, 64));
    }
    if (c == 0) { fmean[grow] = su * (1.f / 64.f); fmax[grow] = mv; }
  }
}

// ---------- fused tail (sa+oproj+LN1+FFN+LN2) + qkv(l+1)+rope ----------
__global__ __launch_bounds__(256) void tailqkv_kernel(
    const float* __restrict__ ctx, const float* __restrict__ fmean,
    const float* __restrict__ fmax, const float* __restrict__ t_sa_w,
    const float* __restrict__ t_o_w, const float* __restrict__ t_o_b,
    const float* __restrict__ t_ln1, const float* __restrict__ t_ff1_w,
    const float* __restrict__ t_ff1_b, const float* __restrict__ t_ff2_w,
    const float* __restrict__ t_ff2_b, const float* __restrict__ t_ln2,
    int l, float* __restrict__ Xen, float* __restrict__ Xpr,
    const float* __restrict__ t_qkv_w, const float* __restrict__ t_qkv_b,
    float* __restrict__ Q, float* __restrict__ K, float* __restrict__ V) {
  int t = threadIdx.x;
  int wid = t >> 6, lane = t & 63;
  int row = blockIdx.x * 4 + wid;
  int branch, b, s, S, lrow;
  row_decode(row, branch, b, s, S, lrow);
  int idx = branch * 2 + l;
  const float* sa_w = t_sa_w + idx * 14;
  float sa = 0.f;
  if (lane == 0) {
    for (int k = 0; k < 7; ++k) {
      int p = s + k - 3;
      if (p >= 0 && p < S)
        sa += fmean[row - s + p] * sa_w[k] + fmax[row - s + p] * sa_w[7 + k];
    }
    sa = 1.f / (1.f + expf(-sa));
  }
  sa = __shfl(sa, 0, 64);
  __shared__ float rowv[4][64], xr[4][64], h[4][256], qs[4][64], ks[4][64];
  rowv[wid][lane] = ctx[(size_t)row * 64 + lane] * sa;
  __syncthreads();
  const float* o_w = t_o_w + (size_t)idx * 4096;
  float o = t_o_b[idx * 64 + lane];
  for (int c = 0; c < 64; ++c) o += rowv[wid][c] * o_w[c * 64 + lane];
  float* X = branch ? Xpr : Xen;
  float r = X[(size_t)lrow * 64 + lane] + o;
  float mu = r;
  for (int of = 32; of; of >>= 1) mu += __shfl_xor(mu, of, 64);
  mu *= (1.f / 64.f);
  float d = r - mu;
  float var = d * d;
  for (int of = 32; of; of >>= 1) var += __shfl_xor(var, of, 64);
  var *= (1.f / 64.f);
  const float* ln1 = t_ln1 + idx * 128;
  float x1 = d * rsqrtf(var + 1e-5f) * ln1[lane] + ln1[64 + lane];
  xr[wid][lane] = x1;
  __syncthreads();
  const float* W1 = t_ff1_w + (size_t)idx * 16384;
  float a0 = t_ff1_b[idx * 256 + t], a1 = a0, a2 = a0, a3 = a0;
  for (int c = 0; c < 64; ++c) {
    float w = W1[c * 256 + t];
    a0 += xr[0][c] * w; a1 += xr[1][c] * w; a2 += xr[2][c] * w; a3 += xr[3][c] * w;
  }
  h[0][t] = fmaxf(a0, 0.f); h[1][t] = fmaxf(a1, 0.f);
  h[2][t] = fmaxf(a2, 0.f); h[3][t] = fmaxf(a3, 0.f);
  __syncthreads();
  const float* W2 = t_ff2_w + (size_t)idx * 16384;
  float o2 = t_ff2_b[idx * 64 + lane];
  for (int j = 0; j < 256; ++j) o2 += h[wid][j] * W2[j * 64 + lane];
  float r2 = x1 + o2;
  mu = r2;
  for (int of = 32; of; of >>= 1) mu += __shfl_xor(mu, of, 64);
  mu *= (1.f / 64.f);
  d = r2 - mu;
  var = d * d;
  for (int of = 32; of; of >>= 1) var += __shfl_xor(var, of, 64);
  var *= (1.f / 64.f);
  const float* ln2 = t_ln2 + idx * 128;
  float fv = d * rsqrtf(var + 1e-5f) * ln2[lane] + ln2[64 + lane];
  X[(size_t)lrow * 64 + lane] = fv;
  xr[wid][lane] = fv;
  __syncthreads();
  // qkv for layer l+1
  int idx2 = branch * 2 + l + 1;
  const float* W = t_qkv_w + (size_t)idx2 * 3 * 4096;
  const float* qb_ = t_qkv_b + idx2 * 192;
  float q = qb_[lane], k = qb_[64 + lane], v = qb_[128 + lane];
  for (int c = 0; c < 64; ++c) {
    float xc = xr[wid][c];
    q += xc * W[c * 64 + lane];
    k += xc * W[4096 + c * 64 + lane];
    v += xc * W[8192 + c * 64 + lane];
  }
  qs[wid][lane] = q; ks[wid][lane] = k;
  V[(size_t)row * 64 + lane] = v;
  __syncthreads();
  int j = lane & 7;
  int p = j >> 1;
  float inv = powf(10000.f, -(float)p * 0.25f);
  float ang = (float)s * inv;
  float cc = cosf(ang), ss = sinf(ang);
  float qo, ko;
  if ((j & 1) == 0) {
    qo = qs[wid][lane] * cc - qs[wid][lane + 1] * ss;
    ko = ks[wid][lane] * cc - ks[wid][lane + 1] * ss;
  } else {
    qo = qs[wid][lane - 1] * ss + qs[wid][lane] * cc;
    ko = ks[wid][lane - 1] * ss + ks[wid][lane] * cc;
  }
  Q[(size_t)row * 64 + lane] = qo;
  K[(size_t)row * 64 + lane] = ko;
}

// ---------- fused tail (l=1) + crossQKV + selfQKV(pr) ----------
__global__ __launch_bounds__(256) void tailcross_kernel(
    const float* __restrict__ ctx, const float* __restrict__ fmean,
    const float* __restrict__ fmax, const float* __restrict__ t_sa_w,
    const float* __restrict__ t_o_w, const float* __restrict__ t_o_b,
    const float* __restrict__ t_ln1, const float* __restrict__ t_ff1_w,
    const float* __restrict__ t_ff1_b, const float* __restrict__ t_ff2_w,
    const float* __restrict__ t_ff2_b, const float* __restrict__ t_ln2,
    float* __restrict__ Xen, float* __restrict__ Xpr,
    const float* __restrict__ Wt, const float* __restrict__ cib,
    const float* __restrict__ sib,
    float* __restrict__ Q, float* __restrict__ K, float* __restrict__ V) {
  int t = threadIdx.x;
  int wid = t >> 6, lane = t & 63;
  int row = blockIdx.x * 4 + wid;
  int branch, b, s, S, lrow;
  row_decode(row, branch, b, s, S, lrow);
  int idx = branch * 2 + 1;
  const float* sa_w = t_sa_w + idx * 14;
  float sa = 0.f;
  if (lane == 0) {
    for (int k = 0; k < 7; ++k) {
      int p = s + k - 3;
      if (p >= 0 && p < S)
        sa += fmean[row - s + p] * sa_w[k] + fmax[row - s + p] * sa_w[7 + k];
    }
    sa = 1.f / (1.f + expf(-sa));
  }
  sa = __shfl(sa, 0, 64);
  __shared__ float rowv[4][64], xr[4][64], h[4][256];
  rowv[wid][lane] = ctx[(size_t)row * 64 + lane] * sa;
  __syncthreads();
  const float* o_w = t_o_w + (size_t)idx * 4096;
  float o = t_o_b[idx * 64 + lane];
  for (int c = 0; c < 64; ++c) o += rowv[wid][c] * o_w[c * 64 + lane];
  float* X = branch ? Xpr : Xen;
  float r = X[(size_t)lrow * 64 + lane] + o;
  float mu = r;
  for (int of = 32; of; of >>= 1) mu += __shfl_xor(mu, of, 64);
  mu *= (1.f / 64.f);
  float d = r - mu;
  float var = d * d;
  for (int of = 32; of; of >>= 1) var += __shfl_xor(var, of, 64);
  var *= (1.f / 64.f);
  const float* ln1 = t_ln1 + idx * 128;
  float x1 = d * rsqrtf(var + 1e-5f) * ln1[lane] + ln1[64 + lane];
  xr[wid][lane] = x1;
  __syncthreads();
  const float* W1 = t_ff1_w + (size_t)idx * 16384;
  float a0 = t_ff1_b[idx * 256 + t], a1 = a0, a2 = a0, a3 = a0;
  for (int c = 0; c < 64; ++c) {
    float w = W1[c * 256 + t];
    a0 += xr[0][c] * w; a1 += xr[1][c] * w; a2 += xr[2][c] * w; a3 += xr[3][c] * w;
  }
  h[0][t] = fmaxf(a0, 0.f); h[1][t] = fmaxf(a1, 0.f);
  h[2][t] = fmaxf(a2, 0.f); h[3][t] = fmaxf(a3, 0.f);
  __syncthreads();
  const float* W2 = t_ff2_w + (size_t)idx * 16384;
  float o2 = t_ff2_b[idx * 64 + lane];
  for (int j = 0; j < 256; ++j) o2 += h[wid][j] * W2[j * 64 + lane];
  float r2 = x1 + o2;
  mu = r2;
  for (int of = 32; of; of >>= 1) mu += __shfl_xor(mu, of, 64);
  mu *= (1.f / 64.f);
  d = r2 - mu;
  var = d * d;
  for (int of = 32; of; of >>= 1) var += __shfl_xor(var, of, 64);
  var *= (1.f / 64.f);
  const float* ln2 = t_ln2 + idx * 128;
  float fv = d * rsqrtf(var + 1e-5f) * ln2[lane] + ln2[64 + lane];
  X[(size_t)lrow * 64 + lane] = fv;
  xr[wid][lane] = fv;
  __syncthreads();
  if (branch == 0) {
    // en: cross Q
    float q = cib[lane];
    for (int c = 0; c < 64; ++c) q += xr[wid][c] * Wt[c * 64 + lane];
    Q[(size_t)row * 64 + lane] = q;
  } else {
    // pr: cross K,V + self Q,K,V (into ext region)
    float k = cib[64 + lane], v = cib[128 + lane];
    float q2 = sib[lane], k2 = sib[64 + lane], v2 = sib[128 + lane];
    for (int c = 0; c < 64; ++c) {
      float xc = xr[wid][c];
      k += xc * Wt[4096 + c * 64 + lane];
      v += xc * Wt[8192 + c * 64 + lane];
      q2 += xc * Wt[4 * 4096 + c * 64 + lane];
      k2 += xc * Wt[5 * 4096 + c * 64 + lane];
      v2 += xc * Wt[6 * 4096 + c * 64 + lane];
    }
    K[(size_t)(ROWS_EN + lrow) * 64 + lane] = k;
    V[(size_t)(ROWS_EN + lrow) * 64 + lane] = v;
    Q[(size_t)(ROWS_ALL + lrow) * 64 + lane] = q2;
    K[(size_t)(ROWS_ALL + lrow) * 64 + lane] = k2;
    V[(size_t)(ROWS_ALL + lrow) * 64 + lane] = v2;
  }
}

// ---------- cross out-proj + selfQKV (en rows only) ----------
__global__ __launch_bounds__(256) void crossout_selfqkv_kernel(
    const float* __restrict__ ctx, const float* __restrict__ Wt,
    const float* __restrict__ cob, const float* __restrict__ sib,
    float* __restrict__ Q, float* __restrict__ K, float* __restrict__ V) {
  int t = threadIdx.x;
  int wid = t >> 6, lane = t & 63;
  int row = blockIdx.x * 4 + wid;  // < ROWS_EN
  __shared__ float xr[4][64], att[4][64];
  xr[wid][lane] = ctx[(size_t)row * 64 + lane];
  __syncthreads();
  float o = cob[lane];
  for (int c = 0; c < 64; ++c) o += xr[wid][c] * Wt[3 * 4096 + c * 64 + lane];
  att[wid][lane] = o;
  __syncthreads();
  float q = sib[lane], k = sib[64 + lane], v = sib[128 + lane];
  for (int c = 0; c < 64; ++c) {
    float xc = att[wid][c];
    q += xc * Wt[4 * 4096 + c * 64 + lane];
    k += xc * Wt[5 * 4096 + c * 64 + lane];
    v += xc * Wt[6 * 4096 + c * 64 + lane];
  }
  Q[(size_t)row * 64 + lane] = q;
  K[(size_t)row * 64 + lane] = k;
  V[(size_t)row * 64 + lane] = v;
}

// ---------- final self out-proj: en rows -> Xen, pr rows(ext) -> PrFin ----------
__global__ __launch_bounds__(256) void final_out_kernel(
    const float* __restrict__ ctx, const float* __restrict__ Wt,
    const float* __restrict__ sob, float* __restrict__ Xen,
    float* __restrict__ PrFin) {
  int t = threadIdx.x;
  int wid = t >> 6, lane = t & 63;
  int row = blockIdx.x * 4 + wid;
  const float* src;
  float* dst;
  int lrow;
  if (row < ROWS_EN) { src = ctx + (size_t)row * 64; dst = Xen; lrow = row; }
  else { lrow = row - ROWS_EN; src = ctx + (size_t)(ROWS_ALL + lrow) * 64; dst = PrFin; }
  __shared__ float xr[4][64];
  xr[wid][lane] = src[lane];
  __syncthreads();
  float o = sob[lane];
  for (int c = 0; c < 64; ++c) o += xr[wid][c] * Wt[7 * 4096 + c * 64 + lane];
  dst[(size_t)lrow * 64 + lane] = o;
}

// ---------- fused head: mean + trig + fourier1 + fourier2 (grid 32 × 512) ----------
__global__ __launch_bounds__(512) void headfuse_kernel(
    const float* __restrict__ en_fin, const float* __restrict__ pr_fin,
    const float* __restrict__ wc1, const float* __restrict__ ws1,
    const float* __restrict__ b1, const float* __restrict__ wc2,
    const float* __restrict__ ws2, const float* __restrict__ b2,
    const float* __restrict__ aloss_acc, float* __restrict__ out) {
  int b = blockIdx.x;
  int t = threadIdx.x;  // 512
  __shared__ float red[4][128], comb_s[128], ct[640], st[640], hid[257], wred[8];
  {
    int col = t & 127, seg = t >> 7;
    float sum = 0.f;
    if (col < 64) {
      for (int s = seg; s < SE; s += 4) sum += en_fin[(size_t)(b * SE + s) * 64 + col];
    } else {
      int c = col - 64;
      for (int s = seg; s < SP; s += 4) sum += pr_fin[(size_t)(b * SP + s) * 64 + c];
    }
    red[seg][col] = sum;
  }
  __syncthreads();
  if (t < 128) {
    float tot = red[0][t] + red[1][t] + red[2][t] + red[3][t];
    float cv = tot / (t < 64 ? (float)SE : (float)SP);
    comb_s[t] = cv;
    out[32 + b * 128 + t] = cv;
  }
  __syncthreads();
  for (int i = t; i < 640; i += 512) {
    int ii = i / 5, g = i - ii * 5;
    float x = comb_s[ii] * (float)(g + 1);
    ct[i] = cosf(x);
    st[i] = sinf(x);
  }
  __syncthreads();
  int w = t >> 6, lane = t & 63;
  for (int o = w; o < 257; o += 8) {
    float acc = 0.f;
    for (int i = lane; i < 640; i += 64)
      acc += ct[i] * wc1[(size_t)o * 640 + i] + st[i] * ws1[(size_t)o * 640 + i];
    for (int off = 32; off; off >>= 1) acc += __shfl_xor(acc, off, 64);
    if (lane == 0) hid[o] = acc + b1[o];
  }
  __syncthreads();
  float acc = 0.f;
  if (t < 257) {
    float x = hid[t];
#pragma unroll
    for (int g = 0; g < 5; ++g) {
      float a = x * (float)(g + 1);
      acc += cosf(a) * wc2[t * 5 + g] + sinf(a) * ws2[t * 5 + g];
    }
  }
  for (int off = 32; off; off >>= 1) acc += __shfl_xor(acc, off, 64);
  if (lane == 0) wred[w] = acc;
  __syncthreads();
  if (t == 0) {
    float tot = b2[0];
#pragma unroll
    for (int g = 0; g < 8; ++g) tot += wred[g];
    out[b] = 1.f / (1.f + expf(-tot));
    if (b == 0) out[4128] = aloss_acc[0];
  }
}

extern "C" void kernel_launch(void* const* d_in, const int* in_sizes, int n_in,
                              void* d_out, int out_size, void* d_ws, size_t ws_size,
                              hipStream_t stream) {
  const int* en_ids = (const int*)d_in[0];
  const int* pr_ids = (const int*)d_in[1];
  const float* emb_en = (const float*)d_in[4];
  const float* emb_pr = (const float*)d_in[5];
  const float* conv_w_en = (const float*)d_in[6];
  const float* conv_b_en = (const float*)d_in[7];
  const float* conv_w_pr = (const float*)d_in[8];
  const float* conv_b_pr = (const float*)d_in[9];
  const float* bn_en = (const float*)d_in[10];
  const float* bn_pr = (const float*)d_in[11];
  const float* t_qkv_w = (const float*)d_in[12];
  const float* t_qkv_b = (const float*)d_in[13];
  const float* t_o_w = (const float*)d_in[14];
  const float* t_o_b = (const float*)d_in[15];
  const float* t_ca_w1 = (const float*)d_in[16];
  const float* t_ca_w2 = (const float*)d_in[17];
  const float* t_sa_w = (const float*)d_in[18];
  const float* t_ff1_w = (const float*)d_in[19];
  const float* t_ff1_b = (const float*)d_in[20];
  const float* t_ff2_w = (const float*)d_in[21];
  const float* t_ff2_b = (const float*)d_in[22];
  const float* t_ln1 = (const float*)d_in[23];
  const float* t_ln2 = (const float*)d_in[24];
  const float* cross_in_w = (const float*)d_in[25];
  const float* cross_in_b = (const float*)d_in[26];
  const float* cross_out_w = (const float*)d_in[27];
  const float* cross_out_b = (const float*)d_in[28];
  const float* self_in_w = (const float*)d_in[29];
  const float* self_in_b = (const float*)d_in[30];
  const float* self_out_w = (const float*)d_in[31];
  const float* self_out_b = (const float*)d_in[32];
  const float* fk1_c = (const float*)d_in[33];
  const float* fk1_s = (const float*)d_in[34];
  const float* fk1_b = (const float*)d_in[35];
  const float* fk2_c = (const float*)d_in[36];
  const float* fk2_s = (const float*)d_in[37];
  const float* fk2_b = (const float*)d_in[38];

  float* out = (float*)d_out;
  float* ws = (float*)d_ws;
  size_t off = 0;
  float* Cen = ws + off;  off += (size_t)4097 * 576;
  float* Cpr = ws + off;  off += (size_t)4097 * 576;
  float* W2en = ws + off; off += 73728;
  float* W2pr = ws + off; off += 73728;
  float* Wt = ws + off;   off += 8 * 4096;
  float* Xen = ws + off;  off += (size_t)ROWS_EN * 64;
  float* Xpr = ws + off;  off += (size_t)ROWS_PR * 64;
  float* Qb = ws + off;   off += (size_t)ROWS_EXT * 64;
  float* Kb = ws + off;   off += (size_t)ROWS_EXT * 64;
  float* Vb = ws + off;   off += (size_t)ROWS_EXT * 64;
  float* Ctx = ws + off;  off += (size_t)ROWS_EXT * 64;
  float* PrFin = ws + off; off += (size_t)ROWS_PR * 64;
  float* Fm = ws + off;   off += ROWS_ALL;
  float* Fx = ws + off;   off += ROWS_ALL;
  float* Al = ws + off;   off += 8;

  const float als_en = 1.f / ((float)BB * 8.f * (float)SE * (float)SE);
  const float als_pr = 1.f / ((float)BB * 8.f * (float)SP * (float)SP);

  // 1. setup
  prep_kernel<<<584, 256, 0, stream>>>(conv_w_en, conv_w_pr, cross_in_w,
                                       cross_out_w, self_in_w, self_out_w,
                                       W2en, W2pr, Wt, Al);
  // 2. conv table
  conv_table_kernel<<<1026, 192, 0, stream>>>(emb_en, emb_pr, W2en, W2pr, Cen, Cpr);
  // 3. frontend + qkv(l0)
  frontqkv_kernel<<<ROWS_ALL / 4, 256, 0, stream>>>(
      en_ids, pr_ids, Cen, Cpr, conv_b_en, conv_b_pr, bn_en, bn_pr,
      t_qkv_w, t_qkv_b, Xen, Xpr, Qb, Kb, Vb);

  // 4-9. transformer layers
  for (int l = 0; l < 2; ++l) {
    attn_kernel<<<512, 256, 0, stream>>>(Qb, Kb, Vb, Ctx,
                                         256, SE, SE, 0, 0, als_en,
                                         SP, SP, ROWS_EN, ROWS_EN, als_pr, Al);
    cafeat_kernel<<<64, 512, 0, stream>>>(Ctx, t_ca_w1, t_ca_w2, l, Fm, Fx);
    if (l == 0) {
      tailqkv_kernel<<<ROWS_ALL / 4, 256, 0, stream>>>(
          Ctx, Fm, Fx, t_sa_w, t_o_w, t_o_b, t_ln1, t_ff1_w, t_ff1_b,
          t_ff2_w, t_ff2_b, t_ln2, l, Xen, Xpr, t_qkv_w, t_qkv_b, Qb, Kb, Vb);
    } else {
      tailcross_kernel<<<ROWS_ALL / 4, 256, 0, stream>>>(
          Ctx, Fm, Fx, t_sa_w, t_o_w, t_o_b, t_ln1, t_ff1_w, t_ff1_b,
          t_ff2_w, t_ff2_b, t_ln2, Xen, Xpr, Wt, cross_in_b, self_in_b,
          Qb, Kb, Vb);
    }
  }

  // 10. cross attn (en Q x pr K/V) + self attn (pr, ext region) merged
  attn_kernel<<<512, 256, 0, stream>>>(Qb, Kb, Vb, Ctx,
                                       256, SE, SP, 0, ROWS_EN, 0.f,
                                       SP, SP, ROWS_ALL, ROWS_ALL, 0.f, Al);
  // 11. cross out-proj + self QKV (en)
  crossout_selfqkv_kernel<<<ROWS_EN / 4, 256, 0, stream>>>(
      Ctx, Wt, cross_out_b, self_in_b, Qb, Kb, Vb);
  // 12. self attn (en)
  attn_kernel<<<256, 256, 0, stream>>>(Qb, Kb, Vb, Ctx,
                                       256, SE, SE, 0, 0, 0.f,
                                       0, 0, 0, 0, 0.f, Al);
  // 13. final out-proj (en -> Xen, pr(ext) -> PrFin)
  final_out_kernel<<<ROWS_ALL / 4, 256, 0, stream>>>(Ctx, Wt, self_out_b,
                                                     Xen, PrFin);
  // 14. head: mean + trig + fourier1 + fourier2
  headfuse_kernel<<<BB, 512, 0, stream>>>(Xen, PrFin, fk1_c, fk1_s, fk1_b,
                                          fk2_c, fk2_s, fk2_b, Al, out);
}

// Round 12
// 434.229 us; speedup vs baseline: 1.2234x; 1.2234x over previous
//
#include <hip/hip_runtime.h>
#include <math.h>

#define BB 32
#define SE 149
#define SP 99
#define LE_LEN 3000
#define LP_LEN 2000
#define VT 8
#define ROWS_EN (BB * SE)              // 4768
#define ROWS_PR (BB * SP)              // 3168
#define ROWS_ALL (ROWS_EN + ROWS_PR)   // 7936
#define ROWS_EXT (ROWS_ALL + ROWS_PR)  // 11104 (extra region for self-pr)

__device__ __forceinline__ void row_decode(int row, int& branch, int& b,
                                           int& s, int& S, int& lrow) {
  if (row < ROWS_EN) { branch = 0; S = SE; lrow = row; b = row / SE; s = row - b * SE; }
  else { branch = 1; S = SP; lrow = row - ROWS_EN; b = lrow / SP; s = lrow - b * SP; }
}

// ---------- prep: conv_w transposes (en+pr), proj transposes, Al zero ----------
__global__ __launch_bounds__(256) void prep_kernel(
    const float* __restrict__ cw_en, const float* __restrict__ cw_pr,
    const float* __restrict__ cross_in, const float* __restrict__ cross_out,
    const float* __restrict__ self_in, const float* __restrict__ self_out,
    float* __restrict__ W2en, float* __restrict__ W2pr,
    float* __restrict__ Wt, float* __restrict__ Al) {
  int bb = blockIdx.x;
  if (bb == 0 && threadIdx.x == 0) Al[0] = 0.f;
  if (bb < 576) {
    const float* src = (bb < 288) ? cw_en : cw_pr;
    float* dst = (bb < 288) ? W2en : W2pr;
    int i = ((bb < 288) ? bb : bb - 288) * 256 + threadIdx.x;
    int oc = i / 1152, r = i % 1152, ic = r / 9, k = r % 9;
    dst[ic * 576 + k * 64 + oc] = src[i];
  } else {
    int m = bb - 576;  // 0..7
    const float* src = (m < 3) ? cross_in + m * 4096
                     : (m == 3) ? cross_out
                     : (m < 7) ? self_in + (m - 4) * 4096
                     : self_out;
    for (int i = threadIdx.x; i < 4096; i += 256) {
      int o = i >> 6, c = i & 63;
      Wt[m * 4096 + c * 64 + o] = src[i];
    }
  }
}

// ---------- conv table, both branches in one launch ----------
__global__ __launch_bounds__(192) void conv_table_kernel(
    const float* __restrict__ emb_en, const float* __restrict__ emb_pr,
    const float* __restrict__ W2en, const float* __restrict__ W2pr,
    float* __restrict__ Cen, float* __restrict__ Cpr) {
  int blk = blockIdx.x;
  int branch = (blk >= 513);
  const float* emb = branch ? emb_pr : emb_en;
  const float* W2 = branch ? W2pr : W2en;
  float* C = branch ? Cpr : Cen;
  int v0 = (branch ? blk - 513 : blk) * VT;
  __shared__ float e[VT][128];
  int t = threadIdx.x;
  int nv = 4097 - v0; if (nv > VT) nv = VT;
  for (int i = t; i < nv * 128; i += 192) e[i >> 7][i & 127] = emb[v0 * 128 + i];
  __syncthreads();
  float a0[VT], a1[VT], a2[VT];
#pragma unroll
  for (int v = 0; v < VT; ++v) { a0[v] = 0.f; a1[v] = 0.f; a2[v] = 0.f; }
  for (int ic = 0; ic < 128; ++ic) {
    float w0 = W2[ic * 576 + t];
    float w1 = W2[ic * 576 + t + 192];
    float w2 = W2[ic * 576 + t + 384];
#pragma unroll
    for (int v = 0; v < VT; ++v) {
      float ev = e[v][ic];
      a0[v] += ev * w0; a1[v] += ev * w1; a2[v] += ev * w2;
    }
  }
  for (int v = 0; v < nv; ++v) {
    C[(size_t)(v0 + v) * 576 + t] = a0[v];
    C[(size_t)(v0 + v) * 576 + t + 192] = a1[v];
    C[(size_t)(v0 + v) * 576 + t + 384] = a2[v];
  }
}

// ---------- frontend + qkv(l=0) + rope, 4 rows/block ----------
__global__ __launch_bounds__(256) void frontqkv_kernel(
    const int* __restrict__ en_ids, const int* __restrict__ pr_ids,
    const float* __restrict__ Cen, const float* __restrict__ Cpr,
    const float* __restrict__ cb_en, const float* __restrict__ cb_pr,
    const float* __restrict__ bn_en, const float* __restrict__ bn_pr,
    const float* __restrict__ t_qkv_w, const float* __restrict__ t_qkv_b,
    float* __restrict__ Xen, float* __restrict__ Xpr,
    float* __restrict__ Q, float* __restrict__ K, float* __restrict__ V) {
  int t = threadIdx.x;
  int wid = t >> 6, oc = t & 63;
  int row = blockIdx.x * 4 + wid;
  int branch, b, s, S, lrow;
  row_decode(row, branch, b, s, S, lrow);
  const int* ids = branch ? pr_ids : en_ids;
  int Lin = branch ? LP_LEN : LE_LEN;
  const float* C = branch ? Cpr : Cen;
  const float* cb = branch ? cb_pr : cb_en;
  const float* bn = branch ? bn_pr : bn_en;
  float* X = branch ? Xpr : Xen;
  __shared__ int idl[4][28];
  __shared__ float xr[4][64], qs[4][64], ks[4][64];
  if (oc < 28) idl[wid][oc] = ids[b * Lin + s * 20 + oc];
  __syncthreads();
  float bias = cb[oc];
  float m = -INFINITY;
  for (int p = 0; p < 20; ++p) {
    float acc = bias;
#pragma unroll
    for (int k = 0; k < 9; ++k) acc += C[idl[wid][p + k] * 576 + k * 64 + oc];
    acc = fmaxf(acc, 0.f);
    m = fmaxf(m, acc);
  }
  float g = bn[oc], be = bn[64 + oc], mu = bn[128 + oc], var = bn[192 + oc];
  float xv = (m - mu) * rsqrtf(var + 1e-5f) * g + be;
  X[(size_t)lrow * 64 + oc] = xv;
  xr[wid][oc] = xv;
  __syncthreads();
  // qkv for layer 0
  int idx = branch * 2;
  const float* W = t_qkv_w + (size_t)idx * 3 * 4096;
  const float* qb_ = t_qkv_b + idx * 192;
  float q = qb_[oc], k = qb_[64 + oc], v = qb_[128 + oc];
  for (int c = 0; c < 64; ++c) {
    float xc = xr[wid][c];
    q += xc * W[c * 64 + oc];
    k += xc * W[4096 + c * 64 + oc];
    v += xc * W[8192 + c * 64 + oc];
  }
  qs[wid][oc] = q; ks[wid][oc] = k;
  V[row * 64 + oc] = v;
  __syncthreads();
  int j = oc & 7;
  int p = j >> 1;
  float inv = powf(10000.f, -(float)p * 0.25f);
  float ang = (float)s * inv;
  float cc = cosf(ang), ss = sinf(ang);
  float qo, ko;
  if ((j & 1) == 0) {
    qo = qs[wid][oc] * cc - qs[wid][oc + 1] * ss;
    ko = ks[wid][oc] * cc - ks[wid][oc + 1] * ss;
  } else {
    qo = qs[wid][oc - 1] * ss + qs[wid][oc] * cc;
    ko = ks[wid][oc - 1] * ss + ks[wid][oc] * cc;
  }
  Q[row * 64 + oc] = qo;
  K[row * 64 + oc] = ko;
}

// ---------- attention, two sections per launch ----------
__global__ __launch_bounds__(256) void attn_kernel(
    const float* __restrict__ Q, const float* __restrict__ K,
    const float* __restrict__ V, float* __restrict__ ctx,
    int nblk0, int Sq0, int Sk0, int qb0, int kb0, float als0,
    int Sq1, int Sk1, int qb1, int kb1, float als1,
    float* __restrict__ aloss_acc) {
  int blk = blockIdx.x;
  int bh, Sq, Sk, qb, kb; float als;
  if (blk < nblk0) { bh = blk; Sq = Sq0; Sk = Sk0; qb = qb0; kb = kb0; als = als0; }
  else { bh = blk - nblk0; Sq = Sq1; Sk = Sk1; qb = qb1; kb = kb1; als = als1; }
  int b = bh >> 3, h = bh & 7;
  __shared__ float kk[160 * 8], vv[160 * 8];
  int t = threadIdx.x;
  for (int i = t; i < Sk * 8; i += 256) {
    int r = i >> 3, j = i & 7;
    kk[i] = K[(kb + b * Sk + r) * 64 + h * 8 + j];
    vv[i] = V[(kb + b * Sk + r) * 64 + h * 8 + j];
  }
  __syncthreads();
  float rowsum2 = 0.f;
  if (t < Sq) {
    float q[8];
#pragma unroll
    for (int j = 0; j < 8; ++j) q[j] = Q[(qb + b * Sq + t) * 64 + h * 8 + j];
    float m = -INFINITY, sum = 0.f, sum2 = 0.f, acc[8];
#pragma unroll
    for (int j = 0; j < 8; ++j) acc[j] = 0.f;
    const float sc = 0.35355339059327373f;
    for (int kki = 0; kki < Sk; ++kki) {
      float sdot = 0.f;
#pragma unroll
      for (int j = 0; j < 8; ++j) sdot += q[j] * kk[kki * 8 + j];
      sdot *= sc;
      if (sdot > m) {
        float f = expf(m - sdot);
        sum *= f; sum2 *= f * f;
#pragma unroll
        for (int j = 0; j < 8; ++j) acc[j] *= f;
        m = sdot;
      }
      float e = expf(sdot - m);
      sum += e; sum2 += e * e;
#pragma unroll
      for (int j = 0; j < 8; ++j) acc[j] += e * vv[kki * 8 + j];
    }
    float invs = 1.f / sum;
#pragma unroll
    for (int j = 0; j < 8; ++j)
      ctx[(qb + b * Sq + t) * 64 + h * 8 + j] = acc[j] * invs;
    rowsum2 = sum2 * invs * invs;
  }
  if (als != 0.f) {
    float wsum = rowsum2;
    for (int off = 32; off; off >>= 1) wsum += __shfl_down(wsum, off, 64);
    __shared__ float wred[4];
    if ((t & 63) == 0) wred[t >> 6] = wsum;
    __syncthreads();
    if (t == 0) {
      float tot = wred[0] + wred[1] + wred[2] + wred[3];
      atomicAdd(aloss_acc, tot * als);
    }
  }
}

// ---------- fused channel attention + apply + spatial feat (grid 64 × 512) ----------
__global__ __launch_bounds__(512) void cafeat_kernel(
    float* __restrict__ ctx, const float* __restrict__ t_ca_w1,
    const float* __restrict__ t_ca_w2, int l,
    float* __restrict__ fmean, float* __restrict__ fmax) {
  int bp = blockIdx.x;  // 0..63
  int branch = bp >> 5, b = bp & 31;
  int S = branch ? SP : SE;
  int base = branch ? ROWS_EN : 0;
  int idx = branch * 2 + l;
  const float* W1 = t_ca_w1 + idx * 512;
  const float* W2 = t_ca_w2 + idx * 512;
  int t = threadIdx.x;  // 512
  int c = t & 63, seg = t >> 6;  // 8 segments (each seg = one wave)
  float sum = 0.f, mx = -INFINITY;
  for (int s = seg; s < S; s += 8) {
    float v = ctx[(size_t)(base + b * S + s) * 64 + c];
    sum += v; mx = fmaxf(mx, v);
  }
  __shared__ float ssum[8][64], smx[8][64];
  ssum[seg][c] = sum; smx[seg][c] = mx;
  __syncthreads();
  __shared__ float avg_l[64], mx_l[64], ha[8], hm[8], ca_s[64];
  if (t < 64) {
    float a = 0.f, m = -INFINITY;
#pragma unroll
    for (int g = 0; g < 8; ++g) { a += ssum[g][t]; m = fmaxf(m, smx[g][t]); }
    avg_l[t] = a / (float)S; mx_l[t] = m;
  }
  __syncthreads();
  if (t < 8) {
    float a = 0.f, m2 = 0.f;
    for (int i = 0; i < 64; ++i) {
      a += avg_l[i] * W1[i * 8 + t];
      m2 += mx_l[i] * W1[i * 8 + t];
    }
    ha[t] = fmaxf(a, 0.f); hm[t] = fmaxf(m2, 0.f);
  }
  __syncthreads();
  if (t < 64) {
    float o = 0.f;
#pragma unroll
    for (int j = 0; j < 8; ++j) o += (ha[j] + hm[j]) * W2[j * 64 + t];
    ca_s[t] = 1.f / (1.f + expf(-o));
  }
  __syncthreads();
  float cav = ca_s[c];
  for (int s = seg; s < S; s += 8) {
    int grow = base + b * S + s;
    float v = ctx[(size_t)grow * 64 + c] * cav;
    ctx[(size_t)grow * 64 + c] = v;
    float su = v, mv = v;
    for (int off = 32; off; off >>= 1) {
      su += __shfl_xor(su, off, 64);
      mv = fmaxf(mv, __shfl_xor(mv, off, 64));
    }
    if (c == 0) { fmean[grow] = su * (1.f / 64.f); fmax[grow] = mv; }
  }
}

// ---------- fused tail (sa+oproj+LN1+FFN+LN2) + qkv(l+1)+rope ----------
__global__ __launch_bounds__(256) void tailqkv_kernel(
    const float* __restrict__ ctx, const float* __restrict__ fmean,
    const float* __restrict__ fmax, const float* __restrict__ t_sa_w,
    const float* __restrict__ t_o_w, const float* __restrict__ t_o_b,
    const float* __restrict__ t_ln1, const float* __restrict__ t_ff1_w,
    const float* __restrict__ t_ff1_b, const float* __restrict__ t_ff2_w,
    const float* __restrict__ t_ff2_b, const float* __restrict__ t_ln2,
    int l, float* __restrict__ Xen, float* __restrict__ Xpr,
    const float* __restrict__ t_qkv_w, const float* __restrict__ t_qkv_b,
    float* __restrict__ Q, float* __restrict__ K, float* __restrict__ V) {
  int t = threadIdx.x;
  int wid = t >> 6, lane = t & 63;
  int row = blockIdx.x * 4 + wid;
  int branch, b, s, S, lrow;
  row_decode(row, branch, b, s, S, lrow);
  int idx = branch * 2 + l;
  const float* sa_w = t_sa_w + idx * 14;
  float sa = 0.f;
  if (lane == 0) {
    for (int k = 0; k < 7; ++k) {
      int p = s + k - 3;
      if (p >= 0 && p < S)
        sa += fmean[row - s + p] * sa_w[k] + fmax[row - s + p] * sa_w[7 + k];
    }
    sa = 1.f / (1.f + expf(-sa));
  }
  sa = __shfl(sa, 0, 64);
  __shared__ float rowv[4][64], xr[4][64], h[4][256], qs[4][64], ks[4][64];
  rowv[wid][lane] = ctx[(size_t)row * 64 + lane] * sa;
  __syncthreads();
  const float* o_w = t_o_w + (size_t)idx * 4096;
  float o = t_o_b[idx * 64 + lane];
  for (int c = 0; c < 64; ++c) o += rowv[wid][c] * o_w[c * 64 + lane];
  float* X = branch ? Xpr : Xen;
  float r = X[(size_t)lrow * 64 + lane] + o;
  float mu = r;
  for (int of = 32; of; of >>= 1) mu += __shfl_xor(mu, of, 64);
  mu *= (1.f / 64.f);
  float d = r - mu;
  float var = d * d;
  for (int of = 32; of; of >>= 1) var += __shfl_xor(var, of, 64);
  var *= (1.f / 64.f);
  const float* ln1 = t_ln1 + idx * 128;
  float x1 = d * rsqrtf(var + 1e-5f) * ln1[lane] + ln1[64 + lane];
  xr[wid][lane] = x1;
  __syncthreads();
  const float* W1 = t_ff1_w + (size_t)idx * 16384;
  float a0 = t_ff1_b[idx * 256 + t], a1 = a0, a2 = a0, a3 = a0;
  for (int c = 0; c < 64; ++c) {
    float w = W1[c * 256 + t];
    a0 += xr[0][c] * w; a1 += xr[1][c] * w; a2 += xr[2][c] * w; a3 += xr[3][c] * w;
  }
  h[0][t] = fmaxf(a0, 0.f); h[1][t] = fmaxf(a1, 0.f);
  h[2][t] = fmaxf(a2, 0.f); h[3][t] = fmaxf(a3, 0.f);
  __syncthreads();
  const float* W2 = t_ff2_w + (size_t)idx * 16384;
  float o2 = t_ff2_b[idx * 64 + lane];
  for (int j = 0; j < 256; ++j) o2 += h[wid][j] * W2[j * 64 + lane];
  float r2 = x1 + o2;
  mu = r2;
  for (int of = 32; of; of >>= 1) mu += __shfl_xor(mu, of, 64);
  mu *= (1.f / 64.f);
  d = r2 - mu;
  var = d * d;
  for (int of = 32; of; of >>= 1) var += __shfl_xor(var, of, 64);
  var *= (1.f / 64.f);
  const float* ln2 = t_ln2 + idx * 128;
  float fv = d * rsqrtf(var + 1e-5f) * ln2[lane] + ln2[64 + lane];
  X[(size_t)lrow * 64 + lane] = fv;
  xr[wid][lane] = fv;
  __syncthreads();
  // qkv for layer l+1
  int idx2 = branch * 2 + l + 1;
  const float* W = t_qkv_w + (size_t)idx2 * 3 * 4096;
  const float* qb_ = t_qkv_b + idx2 * 192;
  float q = qb_[lane], k = qb_[64 + lane], v = qb_[128 + lane];
  for (int c = 0; c < 64; ++c) {
    float xc = xr[wid][c];
    q += xc * W[c * 64 + lane];
    k += xc * W[4096 + c * 64 + lane];
    v += xc * W[8192 + c * 64 + lane];
  }
  qs[wid][lane] = q; ks[wid][lane] = k;
  V[(size_t)row * 64 + lane] = v;
  __syncthreads();
  int j = lane & 7;
  int p = j >> 1;
  float inv = powf(10000.f, -(float)p * 0.25f);
  float ang = (float)s * inv;
  float cc = cosf(ang), ss = sinf(ang);
  float qo, ko;
  if ((j & 1) == 0) {
    qo = qs[wid][lane] * cc - qs[wid][lane + 1] * ss;
    ko = ks[wid][lane] * cc - ks[wid][lane + 1] * ss;
  } else {
    qo = qs[wid][lane - 1] * ss + qs[wid][lane] * cc;
    ko = ks[wid][lane - 1] * ss + ks[wid][lane] * cc;
  }
  Q[(size_t)row * 64 + lane] = qo;
  K[(size_t)row * 64 + lane] = ko;
}

// ---------- fused tail (l=1) + crossQKV + selfQKV(pr) ----------
__global__ __launch_bounds__(256) void tailcross_kernel(
    const float* __restrict__ ctx, const float* __restrict__ fmean,
    const float* __restrict__ fmax, const float* __restrict__ t_sa_w,
    const float* __restrict__ t_o_w, const float* __restrict__ t_o_b,
    const float* __restrict__ t_ln1, const float* __restrict__ t_ff1_w,
    const float* __restrict__ t_ff1_b, const float* __restrict__ t_ff2_w,
    const float* __restrict__ t_ff2_b, const float* __restrict__ t_ln2,
    float* __restrict__ Xen, float* __restrict__ Xpr,
    const float* __restrict__ Wt, const float* __restrict__ cib,
    const float* __restrict__ sib,
    float* __restrict__ Q, float* __restrict__ K, float* __restrict__ V) {
  int t = threadIdx.x;
  int wid = t >> 6, lane = t & 63;
  int row = blockIdx.x * 4 + wid;
  int branch, b, s, S, lrow;
  row_decode(row, branch, b, s, S, lrow);
  int idx = branch * 2 + 1;
  const float* sa_w = t_sa_w + idx * 14;
  float sa = 0.f;
  if (lane == 0) {
    for (int k = 0; k < 7; ++k) {
      int p = s + k - 3;
      if (p >= 0 && p < S)
        sa += fmean[row - s + p] * sa_w[k] + fmax[row - s + p] * sa_w[7 + k];
    }
    sa = 1.f / (1.f + expf(-sa));
  }
  sa = __shfl(sa, 0, 64);
  __shared__ float rowv[4][64], xr[4][64], h[4][256];
  rowv[wid][lane] = ctx[(size_t)row * 64 + lane] * sa;
  __syncthreads();
  const float* o_w = t_o_w + (size_t)idx * 4096;
  float o = t_o_b[idx * 64 + lane];
  for (int c = 0; c < 64; ++c) o += rowv[wid][c] * o_w[c * 64 + lane];
  float* X = branch ? Xpr : Xen;
  float r = X[(size_t)lrow * 64 + lane] + o;
  float mu = r;
  for (int of = 32; of; of >>= 1) mu += __shfl_xor(mu, of, 64);
  mu *= (1.f / 64.f);
  float d = r - mu;
  float var = d * d;
  for (int of = 32; of; of >>= 1) var += __shfl_xor(var, of, 64);
  var *= (1.f / 64.f);
  const float* ln1 = t_ln1 + idx * 128;
  float x1 = d * rsqrtf(var + 1e-5f) * ln1[lane] + ln1[64 + lane];
  xr[wid][lane] = x1;
  __syncthreads();
  const float* W1 = t_ff1_w + (size_t)idx * 16384;
  float a0 = t_ff1_b[idx * 256 + t], a1 = a0, a2 = a0, a3 = a0;
  for (int c = 0; c < 64; ++c) {
    float w = W1[c * 256 + t];
    a0 += xr[0][c] * w; a1 += xr[1][c] * w; a2 += xr[2][c] * w; a3 += xr[3][c] * w;
  }
  h[0][t] = fmaxf(a0, 0.f); h[1][t] = fmaxf(a1, 0.f);
  h[2][t] = fmaxf(a2, 0.f); h[3][t] = fmaxf(a3, 0.f);
  __syncthreads();
  const float* W2 = t_ff2_w + (size_t)idx * 16384;
  float o2 = t_ff2_b[idx * 64 + lane];
  for (int j = 0; j < 256; ++j) o2 += h[wid][j] * W2[j * 64 + lane];
  float r2 = x1 + o2;
  mu = r2;
  for (int of = 32; of; of >>= 1) mu += __shfl_xor(mu, of, 64);
  mu *= (1.f / 64.f);
  d = r2 - mu;
  var = d * d;
  for (int of = 32; of; of >>= 1) var += __shfl_xor(var, of, 64);
  var *= (1.f / 64.f);
  const float* ln2 = t_ln2 + idx * 128;
  float fv = d * rsqrtf(var + 1e-5f) * ln2[lane] + ln2[64 + lane];
  X[(size_t)lrow * 64 + lane] = fv;
  xr[wid][lane] = fv;
  __syncthreads();
  if (branch == 0) {
    // en: cross Q
    float q = cib[lane];
    for (int c = 0; c < 64; ++c) q += xr[wid][c] * Wt[c * 64 + lane];
    Q[(size_t)row * 64 + lane] = q;
  } else {
    // pr: cross K,V + self Q,K,V (into ext region)
    float k = cib[64 + lane], v = cib[128 + lane];
    float q2 = sib[lane], k2 = sib[64 + lane], v2 = sib[128 + lane];
    for (int c = 0; c < 64; ++c) {
      float xc = xr[wid][c];
      k += xc * Wt[4096 + c * 64 + lane];
      v += xc * Wt[8192 + c * 64 + lane];
      q2 += xc * Wt[4 * 4096 + c * 64 + lane];
      k2 += xc * Wt[5 * 4096 + c * 64 + lane];
      v2 += xc * Wt[6 * 4096 + c * 64 + lane];
    }
    K[(size_t)(ROWS_EN + lrow) * 64 + lane] = k;
    V[(size_t)(ROWS_EN + lrow) * 64 + lane] = v;
    Q[(size_t)(ROWS_ALL + lrow) * 64 + lane] = q2;
    K[(size_t)(ROWS_ALL + lrow) * 64 + lane] = k2;
    V[(size_t)(ROWS_ALL + lrow) * 64 + lane] = v2;
  }
}

// ---------- cross out-proj + selfQKV (en rows only) ----------
__global__ __launch_bounds__(256) void crossout_selfqkv_kernel(
    const float* __restrict__ ctx, const float* __restrict__ Wt,
    const float* __restrict__ cob, const float* __restrict__ sib,
    float* __restrict__ Q, float* __restrict__ K, float* __restrict__ V) {
  int t = threadIdx.x;
  int wid = t >> 6, lane = t & 63;
  int row = blockIdx.x * 4 + wid;  // < ROWS_EN
  __shared__ float xr[4][64], att[4][64];
  xr[wid][lane] = ctx[(size_t)row * 64 + lane];
  __syncthreads();
  float o = cob[lane];
  for (int c = 0; c < 64; ++c) o += xr[wid][c] * Wt[3 * 4096 + c * 64 + lane];
  att[wid][lane] = o;
  __syncthreads();
  float q = sib[lane], k = sib[64 + lane], v = sib[128 + lane];
  for (int c = 0; c < 64; ++c) {
    float xc = att[wid][c];
    q += xc * Wt[4 * 4096 + c * 64 + lane];
    k += xc * Wt[5 * 4096 + c * 64 + lane];
    v += xc * Wt[6 * 4096 + c * 64 + lane];
  }
  Q[(size_t)row * 64 + lane] = q;
  K[(size_t)row * 64 + lane] = k;
  V[(size_t)row * 64 + lane] = v;
}

// ---------- final self out-proj: en rows -> Xen, pr rows(ext) -> PrFin ----------
__global__ __launch_bounds__(256) void final_out_kernel(
    const float* __restrict__ ctx, const float* __restrict__ Wt,
    const float* __restrict__ sob, float* __restrict__ Xen,
    float* __restrict__ PrFin) {
  int t = threadIdx.x;
  int wid = t >> 6, lane = t & 63;
  int row = blockIdx.x * 4 + wid;
  const float* src;
  float* dst;
  int lrow;
  if (row < ROWS_EN) { src = ctx + (size_t)row * 64; dst = Xen; lrow = row; }
  else { lrow = row - ROWS_EN; src = ctx + (size_t)(ROWS_ALL + lrow) * 64; dst = PrFin; }
  __shared__ float xr[4][64];
  xr[wid][lane] = src[lane];
  __syncthreads();
  float o = sob[lane];
  for (int c = 0; c < 64; ++c) o += xr[wid][c] * Wt[7 * 4096 + c * 64 + lane];
  dst[(size_t)lrow * 64 + lane] = o;
}

// ---------- mean over sequence -> combined + fourier trig table ----------
__global__ __launch_bounds__(512) void mean_trig_kernel(
    const float* __restrict__ en_fin, const float* __restrict__ pr_fin,
    float* __restrict__ comb, float* __restrict__ trig) {
  int b = blockIdx.x;
  int t = threadIdx.x;
  int col = t & 127, seg = t >> 7;
  float sum = 0.f;
  if (col < 64) {
    for (int s = seg; s < SE; s += 4) sum += en_fin[(size_t)(b * SE + s) * 64 + col];
  } else {
    int c = col - 64;
    for (int s = seg; s < SP; s += 4) sum += pr_fin[(size_t)(b * SP + s) * 64 + c];
  }
  __shared__ float red[4][128];
  __shared__ float comb_s[128];
  red[seg][col] = sum;
  __syncthreads();
  if (t < 128) {
    float tot = red[0][t] + red[1][t] + red[2][t] + red[3][t];
    float cv = tot / (t < 64 ? (float)SE : (float)SP);
    comb_s[t] = cv;
    comb[b * 128 + t] = cv;
  }
  __syncthreads();
  for (int i = t; i < 640; i += 512) {
    int ii = i / 5, g = i - ii * 5;
    float x = comb_s[ii] * (float)(g + 1);
    trig[b * 1280 + i] = cosf(x);
    trig[b * 1280 + 640 + i] = sinf(x);
  }
}

// ---------- fourier layer 1 (pure dot over precomputed trig) ----------
__global__ __launch_bounds__(256) void fourier1_kernel(
    const float* __restrict__ trig, const float* __restrict__ wc,
    const float* __restrict__ ws, const float* __restrict__ bias,
    float* __restrict__ hidden) {
  int b = blockIdx.x;
  int t = threadIdx.x;
  int wid = t >> 6, lane = t & 63;
  int o = blockIdx.y * 4 + wid;
  if (o >= 257) return;
  const float* ct = trig + b * 1280;
  const float* st = ct + 640;
  float acc = 0.f;
  for (int i = lane; i < 640; i += 64)
    acc += ct[i] * wc[(size_t)o * 640 + i] + st[i] * ws[(size_t)o * 640 + i];
  for (int off = 32; off; off >>= 1) acc += __shfl_xor(acc, off, 64);
  if (lane == 0) hidden[b * 257 + o] = acc + bias[o];
}

// ---------- fourier layer 2 + sigmoid + aloss writeout ----------
__global__ void fourier2_kernel(const float* __restrict__ hidden,
                                const float* __restrict__ wc,
                                const float* __restrict__ ws,
                                const float* __restrict__ bias,
                                const float* __restrict__ aloss_acc,
                                float* __restrict__ out) {
  int b = blockIdx.x;
  int t = threadIdx.x;  // 320
  float acc = 0.f;
  if (t < 257) {
    float x = hidden[b * 257 + t];
#pragma unroll
    for (int g = 0; g < 5; ++g) {
      float a = x * (float)(g + 1);
      acc += cosf(a) * wc[t * 5 + g] + sinf(a) * ws[t * 5 + g];
    }
  }
  for (int off = 32; off; off >>= 1) acc += __shfl_xor(acc, off, 64);
  __shared__ float wred[5];
  if ((t & 63) == 0) wred[t >> 6] = acc;
  __syncthreads();
  if (t == 0) {
    float tot = wred[0] + wred[1] + wred[2] + wred[3] + wred[4] + bias[0];
    out[b] = 1.f / (1.f + expf(-tot));
    if (b == 0) out[4128] = aloss_acc[0];
  }
}

extern "C" void kernel_launch(void* const* d_in, const int* in_sizes, int n_in,
                              void* d_out, int out_size, void* d_ws, size_t ws_size,
                              hipStream_t stream) {
  const int* en_ids = (const int*)d_in[0];
  const int* pr_ids = (const int*)d_in[1];
  const float* emb_en = (const float*)d_in[4];
  const float* emb_pr = (const float*)d_in[5];
  const float* conv_w_en = (const float*)d_in[6];
  const float* conv_b_en = (const float*)d_in[7];
  const float* conv_w_pr = (const float*)d_in[8];
  const float* conv_b_pr = (const float*)d_in[9];
  const float* bn_en = (const float*)d_in[10];
  const float* bn_pr = (const float*)d_in[11];
  const float* t_qkv_w = (const float*)d_in[12];
  const float* t_qkv_b = (const float*)d_in[13];
  const float* t_o_w = (const float*)d_in[14];
  const float* t_o_b = (const float*)d_in[15];
  const float* t_ca_w1 = (const float*)d_in[16];
  const float* t_ca_w2 = (const float*)d_in[17];
  const float* t_sa_w = (const float*)d_in[18];
  const float* t_ff1_w = (const float*)d_in[19];
  const float* t_ff1_b = (const float*)d_in[20];
  const float* t_ff2_w = (const float*)d_in[21];
  const float* t_ff2_b = (const float*)d_in[22];
  const float* t_ln1 = (const float*)d_in[23];
  const float* t_ln2 = (const float*)d_in[24];
  const float* cross_in_w = (const float*)d_in[25];
  const float* cross_in_b = (const float*)d_in[26];
  const float* cross_out_w = (const float*)d_in[27];
  const float* cross_out_b = (const float*)d_in[28];
  const float* self_in_w = (const float*)d_in[29];
  const float* self_in_b = (const float*)d_in[30];
  const float* self_out_w = (const float*)d_in[31];
  const float* self_out_b = (const float*)d_in[32];
  const float* fk1_c = (const float*)d_in[33];
  const float* fk1_s = (const float*)d_in[34];
  const float* fk1_b = (const float*)d_in[35];
  const float* fk2_c = (const float*)d_in[36];
  const float* fk2_s = (const float*)d_in[37];
  const float* fk2_b = (const float*)d_in[38];

  float* out = (float*)d_out;
  float* ws = (float*)d_ws;
  size_t off = 0;
  float* Cen = ws + off;  off += (size_t)4097 * 576;
  float* Cpr = ws + off;  off += (size_t)4097 * 576;
  float* W2en = ws + off; off += 73728;
  float* W2pr = ws + off; off += 73728;
  float* Wt = ws + off;   off += 8 * 4096;
  float* Xen = ws + off;  off += (size_t)ROWS_EN * 64;
  float* Xpr = ws + off;  off += (size_t)ROWS_PR * 64;
  float* Qb = ws + off;   off += (size_t)ROWS_EXT * 64;
  float* Kb = ws + off;   off += (size_t)ROWS_EXT * 64;
  float* Vb = ws + off;   off += (size_t)ROWS_EXT * 64;
  float* Ctx = ws + off;  off += (size_t)ROWS_EXT * 64;
  float* PrFin = ws + off; off += (size_t)ROWS_PR * 64;
  float* Fm = ws + off;   off += ROWS_ALL;
  float* Fx = ws + off;   off += ROWS_ALL;
  float* Hid = ws + off;  off += BB * 257;
  float* Trig = ws + off; off += (size_t)BB * 1280;
  float* Al = ws + off;   off += 8;

  const float als_en = 1.f / ((float)BB * 8.f * (float)SE * (float)SE);
  const float als_pr = 1.f / ((float)BB * 8.f * (float)SP * (float)SP);

  // 1. setup
  prep_kernel<<<584, 256, 0, stream>>>(conv_w_en, conv_w_pr, cross_in_w,
                                       cross_out_w, self_in_w, self_out_w,
                                       W2en, W2pr, Wt, Al);
  // 2. conv table
  conv_table_kernel<<<1026, 192, 0, stream>>>(emb_en, emb_pr, W2en, W2pr, Cen, Cpr);
  // 3. frontend + qkv(l0)
  frontqkv_kernel<<<ROWS_ALL / 4, 256, 0, stream>>>(
      en_ids, pr_ids, Cen, Cpr, conv_b_en, conv_b_pr, bn_en, bn_pr,
      t_qkv_w, t_qkv_b, Xen, Xpr, Qb, Kb, Vb);

  // 4-9. transformer layers
  for (int l = 0; l < 2; ++l) {
    attn_kernel<<<512, 256, 0, stream>>>(Qb, Kb, Vb, Ctx,
                                         256, SE, SE, 0, 0, als_en,
                                         SP, SP, ROWS_EN, ROWS_EN, als_pr, Al);
    cafeat_kernel<<<64, 512, 0, stream>>>(Ctx, t_ca_w1, t_ca_w2, l, Fm, Fx);
    if (l == 0) {
      tailqkv_kernel<<<ROWS_ALL / 4, 256, 0, stream>>>(
          Ctx, Fm, Fx, t_sa_w, t_o_w, t_o_b, t_ln1, t_ff1_w, t_ff1_b,
          t_ff2_w, t_ff2_b, t_ln2, l, Xen, Xpr, t_qkv_w, t_qkv_b, Qb, Kb, Vb);
    } else {
      tailcross_kernel<<<ROWS_ALL / 4, 256, 0, stream>>>(
          Ctx, Fm, Fx, t_sa_w, t_o_w, t_o_b, t_ln1, t_ff1_w, t_ff1_b,
          t_ff2_w, t_ff2_b, t_ln2, Xen, Xpr, Wt, cross_in_b, self_in_b,
          Qb, Kb, Vb);
    }
  }

  // 10. cross attn (en Q x pr K/V) + self attn (pr, ext region) merged
  attn_kernel<<<512, 256, 0, stream>>>(Qb, Kb, Vb, Ctx,
                                       256, SE, SP, 0, ROWS_EN, 0.f,
                                       SP, SP, ROWS_ALL, ROWS_ALL, 0.f, Al);
  // 11. cross out-proj + self QKV (en)
  crossout_selfqkv_kernel<<<ROWS_EN / 4, 256, 0, stream>>>(
      Ctx, Wt, cross_out_b, self_in_b, Qb, Kb, Vb);
  // 12. self attn (en)
  attn_kernel<<<256, 256, 0, stream>>>(Qb, Kb, Vb, Ctx,
                                       256, SE, SE, 0, 0, 0.f,
                                       0, 0, 0, 0, 0.f, Al);
  // 13. final out-proj (en -> Xen, pr(ext) -> PrFin)
  final_out_kernel<<<ROWS_ALL / 4, 256, 0, stream>>>(Ctx, Wt, self_out_b,
                                                     Xen, PrFin);
  // 14-16. head: mean+trig, fourier1 (wide grid), fourier2
  mean_trig_kernel<<<BB, 512, 0, stream>>>(Xen, PrFin, out + 32, Trig);
  fourier1_kernel<<<dim3(BB, 65), 256, 0, stream>>>(Trig, fk1_c, fk1_s,
                                                    fk1_b, Hid);
  fourier2_kernel<<<BB, 320, 0, stream>>>(Hid, fk2_c, fk2_s, fk2_b, Al, out);
}

// Round 13
// 360.918 us; speedup vs baseline: 1.4718x; 1.2031x over previous
//
#include <hip/hip_runtime.h>
#include <math.h>

#define BB 32
#define SE 149
#define SP 99
#define LE_LEN 3000
#define LP_LEN 2000
#define VT 8
#define ROWS_EN (BB * SE)          // 4768
#define ROWS_PR (BB * SP)          // 3168
#define ROWS_ALL (ROWS_EN + ROWS_PR)  // 7936

__device__ __forceinline__ void row_decode(int row, int& branch, int& b,
                                           int& s, int& S, int& lrow) {
  if (row < ROWS_EN) { branch = 0; S = SE; lrow = row; b = row / SE; s = row - b * SE; }
  else { branch = 1; S = SP; lrow = row - ROWS_EN; b = lrow / SP; s = lrow - b * SP; }
}

// ---------- prep: conv_w transposes (en+pr), proj transposes, Al zero ----------
__global__ __launch_bounds__(256) void prep_kernel(
    const float* __restrict__ cw_en, const float* __restrict__ cw_pr,
    const float* __restrict__ cross_in, const float* __restrict__ cross_out,
    const float* __restrict__ self_in, const float* __restrict__ self_out,
    float* __restrict__ W2en, float* __restrict__ W2pr,
    float* __restrict__ Wt, float* __restrict__ Al) {
  int bb = blockIdx.x;
  if (bb == 0 && threadIdx.x == 0) Al[0] = 0.f;
  if (bb < 576) {
    const float* src = (bb < 288) ? cw_en : cw_pr;
    float* dst = (bb < 288) ? W2en : W2pr;
    int i = ((bb < 288) ? bb : bb - 288) * 256 + threadIdx.x;
    int oc = i / 1152, r = i % 1152, ic = r / 9, k = r % 9;
    dst[ic * 576 + k * 64 + oc] = src[i];
  } else {
    int m = bb - 576;  // 0..7
    const float* src = (m < 3) ? cross_in + m * 4096
                     : (m == 3) ? cross_out
                     : (m < 7) ? self_in + (m - 4) * 4096
                     : self_out;
    for (int i = threadIdx.x; i < 4096; i += 256) {
      int o = i >> 6, c = i & 63;
      Wt[m * 4096 + c * 64 + o] = src[i];
    }
  }
}

// ---------- conv table, both branches in one launch ----------
__global__ __launch_bounds__(192) void conv_table_kernel(
    const float* __restrict__ emb_en, const float* __restrict__ emb_pr,
    const float* __restrict__ W2en, const float* __restrict__ W2pr,
    float* __restrict__ Cen, float* __restrict__ Cpr) {
  int blk = blockIdx.x;
  int branch = (blk >= 513);
  const float* emb = branch ? emb_pr : emb_en;
  const float* W2 = branch ? W2pr : W2en;
  float* C = branch ? Cpr : Cen;
  int v0 = (branch ? blk - 513 : blk) * VT;
  __shared__ float e[VT][128];
  int t = threadIdx.x;
  int nv = 4097 - v0; if (nv > VT) nv = VT;
  for (int i = t; i < nv * 128; i += 192) e[i >> 7][i & 127] = emb[v0 * 128 + i];
  __syncthreads();
  float a0[VT], a1[VT], a2[VT];
#pragma unroll
  for (int v = 0; v < VT; ++v) { a0[v] = 0.f; a1[v] = 0.f; a2[v] = 0.f; }
  for (int ic = 0; ic < 128; ++ic) {
    float w0 = W2[ic * 576 + t];
    float w1 = W2[ic * 576 + t + 192];
    float w2 = W2[ic * 576 + t + 384];
#pragma unroll
    for (int v = 0; v < VT; ++v) {
      float ev = e[v][ic];
      a0[v] += ev * w0; a1[v] += ev * w1; a2[v] += ev * w2;
    }
  }
  for (int v = 0; v < nv; ++v) {
    C[(size_t)(v0 + v) * 576 + t] = a0[v];
    C[(size_t)(v0 + v) * 576 + t + 192] = a1[v];
    C[(size_t)(v0 + v) * 576 + t + 384] = a2[v];
  }
}

// ---------- frontend, both branches, 4 rows/block ----------
__global__ __launch_bounds__(256) void frontend_kernel(
    const int* __restrict__ en_ids, const int* __restrict__ pr_ids,
    const float* __restrict__ Cen, const float* __restrict__ Cpr,
    const float* __restrict__ cb_en, const float* __restrict__ cb_pr,
    const float* __restrict__ bn_en, const float* __restrict__ bn_pr,
    float* __restrict__ Xen, float* __restrict__ Xpr) {
  int t = threadIdx.x;
  int wid = t >> 6, oc = t & 63;
  int row = blockIdx.x * 4 + wid;
  int branch, b, s, S, lrow;
  row_decode(row, branch, b, s, S, lrow);
  const int* ids = branch ? pr_ids : en_ids;
  int Lin = branch ? LP_LEN : LE_LEN;
  const float* C = branch ? Cpr : Cen;
  const float* cb = branch ? cb_pr : cb_en;
  const float* bn = branch ? bn_pr : bn_en;
  float* X = branch ? Xpr : Xen;
  __shared__ int idl[4][28];
  if (oc < 28) idl[wid][oc] = ids[b * Lin + s * 20 + oc];
  __syncthreads();
  float bias = cb[oc];
  float m = -INFINITY;
  for (int p = 0; p < 20; ++p) {
    float acc = bias;
#pragma unroll
    for (int k = 0; k < 9; ++k) acc += C[idl[wid][p + k] * 576 + k * 64 + oc];
    acc = fmaxf(acc, 0.f);
    m = fmaxf(m, acc);
  }
  float g = bn[oc], be = bn[64 + oc], mu = bn[128 + oc], var = bn[192 + oc];
  X[(size_t)lrow * 64 + oc] = (m - mu) * rsqrtf(var + 1e-5f) * g + be;
}

// ---------- qkv + RoPE, both branches, 4 rows/block (2x ILP per output) ----------
__global__ __launch_bounds__(256) void qkv_rope_kernel(
    const float* __restrict__ Xen, const float* __restrict__ Xpr,
    const float* __restrict__ t_qkv_w, const float* __restrict__ t_qkv_b, int l,
    float* __restrict__ Q, float* __restrict__ K, float* __restrict__ V) {
  int t = threadIdx.x;
  int wid = t >> 6, oc = t & 63;
  int row = blockIdx.x * 4 + wid;
  int branch, b, s, S, lrow;
  row_decode(row, branch, b, s, S, lrow);
  const float* X = branch ? Xpr : Xen;
  int idx = branch * 2 + l;
  const float* W = t_qkv_w + (size_t)idx * 3 * 4096;
  const float* bias = t_qkv_b + idx * 192;
  __shared__ float xr[4][64], qs[4][64], ks[4][64];
  xr[wid][oc] = X[lrow * 64 + oc];
  __syncthreads();
  float q0 = bias[oc], k0 = bias[64 + oc], v0 = bias[128 + oc];
  float q1 = 0.f, k1 = 0.f, v1 = 0.f;
  for (int c = 0; c < 64; c += 2) {
    float xa = xr[wid][c], xb = xr[wid][c + 1];
    q0 += xa * W[c * 64 + oc];
    q1 += xb * W[(c + 1) * 64 + oc];
    k0 += xa * W[4096 + c * 64 + oc];
    k1 += xb * W[4096 + (c + 1) * 64 + oc];
    v0 += xa * W[8192 + c * 64 + oc];
    v1 += xb * W[8192 + (c + 1) * 64 + oc];
  }
  float q = q0 + q1, k = k0 + k1, v = v0 + v1;
  qs[wid][oc] = q; ks[wid][oc] = k;
  V[row * 64 + oc] = v;
  __syncthreads();
  int j = oc & 7;
  int p = j >> 1;
  float inv = powf(10000.f, -(float)p * 0.25f);
  float ang = (float)s * inv;
  float cc = cosf(ang), ss = sinf(ang);
  float qo, ko;
  if ((j & 1) == 0) {
    qo = qs[wid][oc] * cc - qs[wid][oc + 1] * ss;
    ko = ks[wid][oc] * cc - ks[wid][oc + 1] * ss;
  } else {
    qo = qs[wid][oc - 1] * ss + qs[wid][oc] * cc;
    ko = ks[wid][oc - 1] * ss + ks[wid][oc] * cc;
  }
  Q[row * 64 + oc] = qo;
  K[row * 64 + oc] = ko;
}

// ---------- attention, two sections per launch ----------
__global__ __launch_bounds__(256) void attn_kernel(
    const float* __restrict__ Q, const float* __restrict__ K,
    const float* __restrict__ V, float* __restrict__ ctx,
    int nblk0, int Sq0, int Sk0, int qb0, int kb0, float als0,
    int Sq1, int Sk1, int qb1, int kb1, float als1,
    float* __restrict__ aloss_acc) {
  int blk = blockIdx.x;
  int bh, Sq, Sk, qb, kb; float als;
  if (blk < nblk0) { bh = blk; Sq = Sq0; Sk = Sk0; qb = qb0; kb = kb0; als = als0; }
  else { bh = blk - nblk0; Sq = Sq1; Sk = Sk1; qb = qb1; kb = kb1; als = als1; }
  int b = bh >> 3, h = bh & 7;
  __shared__ float kk[160 * 8], vv[160 * 8];
  int t = threadIdx.x;
  for (int i = t; i < Sk * 8; i += 256) {
    int r = i >> 3, j = i & 7;
    kk[i] = K[(kb + b * Sk + r) * 64 + h * 8 + j];
    vv[i] = V[(kb + b * Sk + r) * 64 + h * 8 + j];
  }
  __syncthreads();
  float rowsum2 = 0.f;
  if (t < Sq) {
    float q[8];
#pragma unroll
    for (int j = 0; j < 8; ++j) q[j] = Q[(qb + b * Sq + t) * 64 + h * 8 + j];
    float m = -INFINITY, sum = 0.f, sum2 = 0.f, acc[8];
#pragma unroll
    for (int j = 0; j < 8; ++j) acc[j] = 0.f;
    const float sc = 0.35355339059327373f;
    for (int kki = 0; kki < Sk; ++kki) {
      float sdot = 0.f;
#pragma unroll
      for (int j = 0; j < 8; ++j) sdot += q[j] * kk[kki * 8 + j];
      sdot *= sc;
      if (sdot > m) {
        float f = expf(m - sdot);
        sum *= f; sum2 *= f * f;
#pragma unroll
        for (int j = 0; j < 8; ++j) acc[j] *= f;
        m = sdot;
      }
      float e = expf(sdot - m);
      sum += e; sum2 += e * e;
#pragma unroll
      for (int j = 0; j < 8; ++j) acc[j] += e * vv[kki * 8 + j];
    }
    float invs = 1.f / sum;
#pragma unroll
    for (int j = 0; j < 8; ++j)
      ctx[(qb + b * Sq + t) * 64 + h * 8 + j] = acc[j] * invs;
    rowsum2 = sum2 * invs * invs;
  }
  if (als != 0.f) {
    float wsum = rowsum2;
    for (int off = 32; off; off >>= 1) wsum += __shfl_down(wsum, off, 64);
    __shared__ float wred[4];
    if ((t & 63) == 0) wred[t >> 6] = wsum;
    __syncthreads();
    if (t == 0) {
      float tot = wred[0] + wred[1] + wred[2] + wred[3];
      atomicAdd(aloss_acc, tot * als);
    }
  }
}

// ---------- channel attention, both branches (grid 64) ----------
__global__ __launch_bounds__(512) void ca_kernel(
    const float* __restrict__ ctx, const float* __restrict__ t_ca_w1,
    const float* __restrict__ t_ca_w2, int l, float* __restrict__ ca) {
  int bp = blockIdx.x;  // 0..63
  int branch = bp >> 5, b = bp & 31;
  int S = branch ? SP : SE;
  int base = branch ? ROWS_EN : 0;
  int idx = branch * 2 + l;
  const float* W1 = t_ca_w1 + idx * 512;
  const float* W2 = t_ca_w2 + idx * 512;
  int t = threadIdx.x;  // 512
  int c = t & 63, seg = t >> 6;
  float sum = 0.f, mx = -INFINITY;
  for (int s = seg; s < S; s += 8) {
    float v = ctx[(size_t)(base + b * S + s) * 64 + c];
    sum += v; mx = fmaxf(mx, v);
  }
  __shared__ float ssum[8][64], smx[8][64];
  ssum[seg][c] = sum; smx[seg][c] = mx;
  __syncthreads();
  __shared__ float avg_l[64], mx_l[64], ha[8], hm[8];
  if (t < 64) {
    float a = 0.f, m = -INFINITY;
#pragma unroll
    for (int g = 0; g < 8; ++g) { a += ssum[g][t]; m = fmaxf(m, smx[g][t]); }
    avg_l[t] = a / (float)S; mx_l[t] = m;
  }
  __syncthreads();
  if (t < 8) {
    float a = 0.f, m2 = 0.f;
    for (int i = 0; i < 64; ++i) {
      a += avg_l[i] * W1[i * 8 + t];
      m2 += mx_l[i] * W1[i * 8 + t];
    }
    ha[t] = fmaxf(a, 0.f); hm[t] = fmaxf(m2, 0.f);
  }
  __syncthreads();
  if (t < 64) {
    float o = 0.f;
#pragma unroll
    for (int j = 0; j < 8; ++j) o += (ha[j] + hm[j]) * W2[j * 64 + t];
    ca[bp * 64 + t] = 1.f / (1.f + expf(-o));
  }
}

// ---------- apply ca + spatial feat, both branches ----------
__global__ __launch_bounds__(256) void feat_kernel(
    float* __restrict__ ctx, const float* __restrict__ ca,
    float* __restrict__ fmean, float* __restrict__ fmax) {
  int row = blockIdx.x * 4 + (threadIdx.x >> 6);
  int branch, b, s, S, lrow;
  row_decode(row, branch, b, s, S, lrow);
  int c = threadIdx.x & 63;
  float v = ctx[row * 64 + c] * ca[(branch * 32 + b) * 64 + c];
  ctx[row * 64 + c] = v;
  float sum = v, mx = v;
  for (int off = 32; off; off >>= 1) {
    sum += __shfl_xor(sum, off, 64);
    mx = fmaxf(mx, __shfl_xor(mx, off, 64));
  }
  if (c == 0) { fmean[row] = sum * (1.f / 64.f); fmax[row] = mx; }
}

// ---------- fused tail: sa + out proj + LN1 + FFN + LN2, 4 rows/block ----------
__global__ __launch_bounds__(256) void tail_kernel(
    const float* __restrict__ ctx, const float* __restrict__ fmean,
    const float* __restrict__ fmax, const float* __restrict__ t_sa_w,
    const float* __restrict__ t_o_w, const float* __restrict__ t_o_b,
    const float* __restrict__ t_ln1, const float* __restrict__ t_ff1_w,
    const float* __restrict__ t_ff1_b, const float* __restrict__ t_ff2_w,
    const float* __restrict__ t_ff2_b, const float* __restrict__ t_ln2,
    int l, float* __restrict__ Xen, float* __restrict__ Xpr) {
  int t = threadIdx.x;
  int wid = t >> 6, lane = t & 63;
  int row = blockIdx.x * 4 + wid;
  int branch, b, s, S, lrow;
  row_decode(row, branch, b, s, S, lrow);
  int idx = branch * 2 + l;
  const float* sa_w = t_sa_w + idx * 14;
  float sa = 0.f;
  if (lane == 0) {
    for (int k = 0; k < 7; ++k) {
      int p = s + k - 3;
      if (p >= 0 && p < S)
        sa += fmean[row - s + p] * sa_w[k] + fmax[row - s + p] * sa_w[7 + k];
    }
    sa = 1.f / (1.f + expf(-sa));
  }
  sa = __shfl(sa, 0, 64);
  __shared__ float rowv[4][64], xr[4][64], h[4][256];
  rowv[wid][lane] = ctx[row * 64 + lane] * sa;
  __syncthreads();
  // out projection (4-acc ILP) + residual + LN1
  const float* o_w = t_o_w + (size_t)idx * 4096;
  float p0 = t_o_b[idx * 64 + lane], p1 = 0.f, p2 = 0.f, p3 = 0.f;
  for (int c = 0; c < 64; c += 4) {
    p0 += rowv[wid][c] * o_w[c * 64 + lane];
    p1 += rowv[wid][c + 1] * o_w[(c + 1) * 64 + lane];
    p2 += rowv[wid][c + 2] * o_w[(c + 2) * 64 + lane];
    p3 += rowv[wid][c + 3] * o_w[(c + 3) * 64 + lane];
  }
  float o = (p0 + p1) + (p2 + p3);
  float* X = branch ? Xpr : Xen;
  float r = X[lrow * 64 + lane] + o;
  float mu = r;
  for (int of = 32; of; of >>= 1) mu += __shfl_xor(mu, of, 64);
  mu *= (1.f / 64.f);
  float d = r - mu;
  float var = d * d;
  for (int of = 32; of; of >>= 1) var += __shfl_xor(var, of, 64);
  var *= (1.f / 64.f);
  const float* ln1 = t_ln1 + idx * 128;
  float x1 = d * rsqrtf(var + 1e-5f) * ln1[lane] + ln1[64 + lane];
  xr[wid][lane] = x1;
  __syncthreads();
  // FFN phase 1: thread t computes hidden j=t for all 4 rows
  const float* W1 = t_ff1_w + (size_t)idx * 16384;
  float a0 = t_ff1_b[idx * 256 + t], a1 = a0, a2 = a0, a3 = a0;
  for (int c = 0; c < 64; ++c) {
    float w = W1[c * 256 + t];
    a0 += xr[0][c] * w; a1 += xr[1][c] * w; a2 += xr[2][c] * w; a3 += xr[3][c] * w;
  }
  h[0][t] = fmaxf(a0, 0.f); h[1][t] = fmaxf(a1, 0.f);
  h[2][t] = fmaxf(a2, 0.f); h[3][t] = fmaxf(a3, 0.f);
  __syncthreads();
  // FFN phase 2 (4-acc ILP) + residual + LN2
  const float* W2 = t_ff2_w + (size_t)idx * 16384;
  float q0 = t_ff2_b[idx * 64 + lane], q1 = 0.f, q2 = 0.f, q3 = 0.f;
  for (int j = 0; j < 256; j += 4) {
    q0 += h[wid][j] * W2[j * 64 + lane];
    q1 += h[wid][j + 1] * W2[(j + 1) * 64 + lane];
    q2 += h[wid][j + 2] * W2[(j + 2) * 64 + lane];
    q3 += h[wid][j + 3] * W2[(j + 3) * 64 + lane];
  }
  float o2 = (q0 + q1) + (q2 + q3);
  float r2 = x1 + o2;
  mu = r2;
  for (int of = 32; of; of >>= 1) mu += __shfl_xor(mu, of, 64);
  mu *= (1.f / 64.f);
  d = r2 - mu;
  var = d * d;
  for (int of = 32; of; of >>= 1) var += __shfl_xor(var, of, 64);
  var *= (1.f / 64.f);
  const float* ln2 = t_ln2 + idx * 128;
  X[lrow * 64 + lane] = d * rsqrtf(var + 1e-5f) * ln2[lane] + ln2[64 + lane];
}

// ---------- cross projections: Q(en) + K,V(pr) in one launch (ILP) ----------
__global__ __launch_bounds__(256) void cross_proj_kernel(
    const float* __restrict__ Xen, const float* __restrict__ Xpr,
    const float* __restrict__ Wt, const float* __restrict__ bias,
    float* __restrict__ Q, float* __restrict__ K, float* __restrict__ V) {
  int t = threadIdx.x;
  int wid = t >> 6, oc = t & 63;
  int blk = blockIdx.x;
  __shared__ float xr[4][64];
  if (blk < ROWS_EN / 4) {
    int row = blk * 4 + wid;
    xr[wid][oc] = Xen[row * 64 + oc];
    __syncthreads();
    float p0 = bias[oc], p1 = 0.f, p2 = 0.f, p3 = 0.f;
    for (int c = 0; c < 64; c += 4) {
      p0 += xr[wid][c] * Wt[c * 64 + oc];
      p1 += xr[wid][c + 1] * Wt[(c + 1) * 64 + oc];
      p2 += xr[wid][c + 2] * Wt[(c + 2) * 64 + oc];
      p3 += xr[wid][c + 3] * Wt[(c + 3) * 64 + oc];
    }
    Q[row * 64 + oc] = (p0 + p1) + (p2 + p3);
  } else {
    int lr = (blk - ROWS_EN / 4) * 4 + wid;
    xr[wid][oc] = Xpr[lr * 64 + oc];
    __syncthreads();
    float k0 = bias[64 + oc], k1 = 0.f, v0 = bias[128 + oc], v1 = 0.f;
    for (int c = 0; c < 64; c += 2) {
      float xa = xr[wid][c], xb = xr[wid][c + 1];
      k0 += xa * Wt[4096 + c * 64 + oc];
      k1 += xb * Wt[4096 + (c + 1) * 64 + oc];
      v0 += xa * Wt[8192 + c * 64 + oc];
      v1 += xb * Wt[8192 + (c + 1) * 64 + oc];
    }
    K[(ROWS_EN + lr) * 64 + oc] = k0 + k1;
    V[(ROWS_EN + lr) * 64 + oc] = v0 + v1;
  }
}

// ---------- self QKV for en(AttEn) + pr(Xpr) in one launch (2x ILP) ----------
__global__ __launch_bounds__(256) void self_qkv_kernel(
    const float* __restrict__ inEn, const float* __restrict__ inPr,
    const float* __restrict__ Wt, const float* __restrict__ bias,
    float* __restrict__ Q, float* __restrict__ K, float* __restrict__ V) {
  int t = threadIdx.x;
  int wid = t >> 6, oc = t & 63;
  int row = blockIdx.x * 4 + wid;
  const float* in; int lrow;
  if (row < ROWS_EN) { in = inEn; lrow = row; }
  else { in = inPr; lrow = row - ROWS_EN; }
  __shared__ float xr[4][64];
  xr[wid][oc] = in[lrow * 64 + oc];
  __syncthreads();
  float q0 = bias[oc], k0 = bias[64 + oc], v0 = bias[128 + oc];
  float q1 = 0.f, k1 = 0.f, v1 = 0.f;
  for (int c = 0; c < 64; c += 2) {
    float xa = xr[wid][c], xb = xr[wid][c + 1];
    q0 += xa * Wt[c * 64 + oc];
    q1 += xb * Wt[(c + 1) * 64 + oc];
    k0 += xa * Wt[4096 + c * 64 + oc];
    k1 += xb * Wt[4096 + (c + 1) * 64 + oc];
    v0 += xa * Wt[8192 + c * 64 + oc];
    v1 += xb * Wt[8192 + (c + 1) * 64 + oc];
  }
  Q[row * 64 + oc] = q0 + q1;
  K[row * 64 + oc] = k0 + k1;
  V[row * 64 + oc] = v0 + v1;
}

// ---------- out projection, en->out0, pr->out1 (4-acc ILP) ----------
__global__ __launch_bounds__(256) void dual_proj_kernel(
    const float* __restrict__ in, const float* __restrict__ Wt,
    const float* __restrict__ bias, float* __restrict__ out0,
    float* __restrict__ out1) {
  int t = threadIdx.x;
  int wid = t >> 6, oc = t & 63;
  int row = blockIdx.x * 4 + wid;
  float* out; int lrow;
  if (row < ROWS_EN) { out = out0; lrow = row; }
  else { out = out1; lrow = row - ROWS_EN; }
  __shared__ float xr[4][64];
  xr[wid][oc] = in[row * 64 + oc];
  __syncthreads();
  float p0 = bias[oc], p1 = 0.f, p2 = 0.f, p3 = 0.f;
  for (int c = 0; c < 64; c += 4) {
    p0 += xr[wid][c] * Wt[c * 64 + oc];
    p1 += xr[wid][c + 1] * Wt[(c + 1) * 64 + oc];
    p2 += xr[wid][c + 2] * Wt[(c + 2) * 64 + oc];
    p3 += xr[wid][c + 3] * Wt[(c + 3) * 64 + oc];
  }
  out[lrow * 64 + oc] = (p0 + p1) + (p2 + p3);
}

// ---------- mean over sequence -> combined + fourier trig table ----------
__global__ __launch_bounds__(512) void mean_trig_kernel(
    const float* __restrict__ en_fin, const float* __restrict__ pr_fin,
    float* __restrict__ comb, float* __restrict__ trig) {
  int b = blockIdx.x;
  int t = threadIdx.x;
  int col = t & 127, seg = t >> 7;
  float sum = 0.f;
  if (col < 64) {
    for (int s = seg; s < SE; s += 4) sum += en_fin[(b * SE + s) * 64 + col];
  } else {
    int c = col - 64;
    for (int s = seg; s < SP; s += 4) sum += pr_fin[(b * SP + s) * 64 + c];
  }
  __shared__ float red[4][128];
  __shared__ float comb_s[128];
  red[seg][col] = sum;
  __syncthreads();
  if (t < 128) {
    float tot = red[0][t] + red[1][t] + red[2][t] + red[3][t];
    float cv = tot / (t < 64 ? (float)SE : (float)SP);
    comb_s[t] = cv;
    comb[b * 128 + t] = cv;
  }
  __syncthreads();
  for (int i = t; i < 640; i += 512) {
    int ii = i / 5, g = i - ii * 5;
    float x = comb_s[ii] * (float)(g + 1);
    trig[b * 1280 + i] = cosf(x);
    trig[b * 1280 + 640 + i] = sinf(x);
  }
}

// ---------- fourier layer 1 (pure dot over precomputed trig) ----------
__global__ __launch_bounds__(256) void fourier1_kernel(
    const float* __restrict__ trig, const float* __restrict__ wc,
    const float* __restrict__ ws, const float* __restrict__ bias,
    float* __restrict__ hidden) {
  int b = blockIdx.x;
  int t = threadIdx.x;
  int wid = t >> 6, lane = t & 63;
  int o = blockIdx.y * 4 + wid;
  if (o >= 257) return;
  const float* ct = trig + b * 1280;
  const float* st = ct + 640;
  float acc = 0.f;
  for (int i = lane; i < 640; i += 64)
    acc += ct[i] * wc[(size_t)o * 640 + i] + st[i] * ws[(size_t)o * 640 + i];
  for (int off = 32; off; off >>= 1) acc += __shfl_xor(acc, off, 64);
  if (lane == 0) hidden[b * 257 + o] = acc + bias[o];
}

// ---------- fourier layer 2 + sigmoid + aloss writeout ----------
__global__ void fourier2_kernel(const float* __restrict__ hidden,
                                const float* __restrict__ wc,
                                const float* __restrict__ ws,
                                const float* __restrict__ bias,
                                const float* __restrict__ aloss_acc,
                                float* __restrict__ out) {
  int b = blockIdx.x;
  int t = threadIdx.x;  // 320
  float acc = 0.f;
  if (t < 257) {
    float x = hidden[b * 257 + t];
#pragma unroll
    for (int g = 0; g < 5; ++g) {
      float a = x * (float)(g + 1);
      acc += cosf(a) * wc[t * 5 + g] + sinf(a) * ws[t * 5 + g];
    }
  }
  for (int off = 32; off; off >>= 1) acc += __shfl_xor(acc, off, 64);
  __shared__ float wred[5];
  if ((t & 63) == 0) wred[t >> 6] = acc;
  __syncthreads();
  if (t == 0) {
    float tot = wred[0] + wred[1] + wred[2] + wred[3] + wred[4] + bias[0];
    out[b] = 1.f / (1.f + expf(-tot));
    if (b == 0) out[4128] = aloss_acc[0];
  }
}

extern "C" void kernel_launch(void* const* d_in, const int* in_sizes, int n_in,
                              void* d_out, int out_size, void* d_ws, size_t ws_size,
                              hipStream_t stream) {
  const int* en_ids = (const int*)d_in[0];
  const int* pr_ids = (const int*)d_in[1];
  const float* emb_en = (const float*)d_in[4];
  const float* emb_pr = (const float*)d_in[5];
  const float* conv_w_en = (const float*)d_in[6];
  const float* conv_b_en = (const float*)d_in[7];
  const float* conv_w_pr = (const float*)d_in[8];
  const float* conv_b_pr = (const float*)d_in[9];
  const float* bn_en = (const float*)d_in[10];
  const float* bn_pr = (const float*)d_in[11];
  const float* t_qkv_w = (const float*)d_in[12];
  const float* t_qkv_b = (const float*)d_in[13];
  const float* t_o_w = (const float*)d_in[14];
  const float* t_o_b = (const float*)d_in[15];
  const float* t_ca_w1 = (const float*)d_in[16];
  const float* t_ca_w2 = (const float*)d_in[17];
  const float* t_sa_w = (const float*)d_in[18];
  const float* t_ff1_w = (const float*)d_in[19];
  const float* t_ff1_b = (const float*)d_in[20];
  const float* t_ff2_w = (const float*)d_in[21];
  const float* t_ff2_b = (const float*)d_in[22];
  const float* t_ln1 = (const float*)d_in[23];
  const float* t_ln2 = (const float*)d_in[24];
  const float* cross_in_w = (const float*)d_in[25];
  const float* cross_in_b = (const float*)d_in[26];
  const float* cross_out_w = (const float*)d_in[27];
  const float* cross_out_b = (const float*)d_in[28];
  const float* self_in_w = (const float*)d_in[29];
  const float* self_in_b = (const float*)d_in[30];
  const float* self_out_w = (const float*)d_in[31];
  const float* self_out_b = (const float*)d_in[32];
  const float* fk1_c = (const float*)d_in[33];
  const float* fk1_s = (const float*)d_in[34];
  const float* fk1_b = (const float*)d_in[35];
  const float* fk2_c = (const float*)d_in[36];
  const float* fk2_s = (const float*)d_in[37];
  const float* fk2_b = (const float*)d_in[38];

  float* out = (float*)d_out;
  float* ws = (float*)d_ws;
  size_t off = 0;
  float* Cen = ws + off;  off += (size_t)4097 * 576;
  float* Cpr = ws + off;  off += (size_t)4097 * 576;
  float* W2en = ws + off; off += 73728;
  float* W2pr = ws + off; off += 73728;
  float* Wt = ws + off;   off += 8 * 4096;
  float* Xen = ws + off;  off += (size_t)ROWS_EN * 64;
  float* Xpr = ws + off;  off += (size_t)ROWS_PR * 64;
  float* Qb = ws + off;   off += (size_t)ROWS_ALL * 64;
  float* Kb = ws + off;   off += (size_t)ROWS_ALL * 64;
  float* Vb = ws + off;   off += (size_t)ROWS_ALL * 64;
  float* Ctx = ws + off;  off += (size_t)ROWS_ALL * 64;
  float* AttEn = ws + off; off += (size_t)ROWS_EN * 64;
  float* PrFin = ws + off; off += (size_t)ROWS_PR * 64;
  float* Fm = ws + off;   off += ROWS_ALL;
  float* Fx = ws + off;   off += ROWS_ALL;
  float* CaB = ws + off;  off += 2 * BB * 64;
  float* Hid = ws + off;  off += BB * 257;
  float* Trig = ws + off; off += (size_t)BB * 1280;
  float* Al = ws + off;   off += 8;

  const float als_en = 1.f / ((float)BB * 8.f * (float)SE * (float)SE);
  const float als_pr = 1.f / ((float)BB * 8.f * (float)SP * (float)SP);

  // setup: transposes + Al zero
  prep_kernel<<<584, 256, 0, stream>>>(conv_w_en, conv_w_pr, cross_in_w,
                                       cross_out_w, self_in_w, self_out_w,
                                       W2en, W2pr, Wt, Al);
  // frontend (both branches)
  conv_table_kernel<<<1026, 192, 0, stream>>>(emb_en, emb_pr, W2en, W2pr, Cen, Cpr);
  frontend_kernel<<<ROWS_ALL / 4, 256, 0, stream>>>(en_ids, pr_ids, Cen, Cpr,
                                                    conv_b_en, conv_b_pr, bn_en,
                                                    bn_pr, Xen, Xpr);

  // transformer layers (both branches per launch)
  for (int l = 0; l < 2; ++l) {
    qkv_rope_kernel<<<ROWS_ALL / 4, 256, 0, stream>>>(Xen, Xpr, t_qkv_w,
                                                      t_qkv_b, l, Qb, Kb, Vb);
    attn_kernel<<<512, 256, 0, stream>>>(Qb, Kb, Vb, Ctx,
                                         256, SE, SE, 0, 0, als_en,
                                         SP, SP, ROWS_EN, ROWS_EN, als_pr, Al);
    ca_kernel<<<64, 512, 0, stream>>>(Ctx, t_ca_w1, t_ca_w2, l, CaB);
    feat_kernel<<<ROWS_ALL / 4, 256, 0, stream>>>(Ctx, CaB, Fm, Fx);
    tail_kernel<<<ROWS_ALL / 4, 256, 0, stream>>>(
        Ctx, Fm, Fx, t_sa_w, t_o_w, t_o_b, t_ln1, t_ff1_w, t_ff1_b,
        t_ff2_w, t_ff2_b, t_ln2, l, Xen, Xpr);
  }

  // cross attention: en_att = mha(en, pr, pr)
  cross_proj_kernel<<<ROWS_ALL / 4, 256, 0, stream>>>(Xen, Xpr, Wt,
                                                      cross_in_b, Qb, Kb, Vb);
  attn_kernel<<<256, 256, 0, stream>>>(Qb, Kb, Vb, Ctx,
                                       256, SE, SP, 0, ROWS_EN, 0.f,
                                       0, 0, 0, 0, 0.f, Al);
  dual_proj_kernel<<<ROWS_EN / 4, 256, 0, stream>>>(Ctx, Wt + 3 * 4096,
                                                    cross_out_b, AttEn, AttEn);

  // self attention: en(AttEn) and pr(Xpr) merged
  self_qkv_kernel<<<ROWS_ALL / 4, 256, 0, stream>>>(AttEn, Xpr, Wt + 4 * 4096,
                                                    self_in_b, Qb, Kb, Vb);
  attn_kernel<<<512, 256, 0, stream>>>(Qb, Kb, Vb, Ctx,
                                       256, SE, SE, 0, 0, 0.f,
                                       SP, SP, ROWS_EN, ROWS_EN, 0.f, Al);
  dual_proj_kernel<<<ROWS_ALL / 4, 256, 0, stream>>>(Ctx, Wt + 7 * 4096,
                                                     self_out_b, Xen, PrFin);

  // combined + fourier head
  mean_trig_kernel<<<BB, 512, 0, stream>>>(Xen, PrFin, out + 32, Trig);
  fourier1_kernel<<<dim3(BB, 65), 256, 0, stream>>>(Trig, fk1_c, fk1_s,
                                                    fk1_b, Hid);
  fourier2_kernel<<<BB, 320, 0, stream>>>(Hid, fk2_c, fk2_s, fk2_b, Al, out);
}

// Round 14
// 325.263 us; speedup vs baseline: 1.6332x; 1.1096x over previous
//
#include <hip/hip_runtime.h>
#include <math.h>

#define BB 32
#define SE 149
#define SP 99
#define LE_LEN 3000
#define LP_LEN 2000
#define VT 8
#define ROWS_EN (BB * SE)          // 4768
#define ROWS_PR (BB * SP)          // 3168
#define ROWS_ALL (ROWS_EN + ROWS_PR)  // 7936

__device__ __forceinline__ void row_decode(int row, int& branch, int& b,
                                           int& s, int& S, int& lrow) {
  if (row < ROWS_EN) { branch = 0; S = SE; lrow = row; b = row / SE; s = row - b * SE; }
  else { branch = 1; S = SP; lrow = row - ROWS_EN; b = lrow / SP; s = lrow - b * SP; }
}

// ---------- prep: conv_w transposes (en+pr), proj transposes, Al zero ----------
__global__ __launch_bounds__(256) void prep_kernel(
    const float* __restrict__ cw_en, const float* __restrict__ cw_pr,
    const float* __restrict__ cross_in, const float* __restrict__ cross_out,
    const float* __restrict__ self_in, const float* __restrict__ self_out,
    float* __restrict__ W2en, float* __restrict__ W2pr,
    float* __restrict__ Wt, float* __restrict__ Al) {
  int bb = blockIdx.x;
  if (bb == 0 && threadIdx.x == 0) Al[0] = 0.f;
  if (bb < 576) {
    const float* src = (bb < 288) ? cw_en : cw_pr;
    float* dst = (bb < 288) ? W2en : W2pr;
    int i = ((bb < 288) ? bb : bb - 288) * 256 + threadIdx.x;
    int oc = i / 1152, r = i % 1152, ic = r / 9, k = r % 9;
    dst[ic * 576 + k * 64 + oc] = src[i];
  } else {
    int m = bb - 576;  // 0..7
    const float* src = (m < 3) ? cross_in + m * 4096
                     : (m == 3) ? cross_out
                     : (m < 7) ? self_in + (m - 4) * 4096
                     : self_out;
    for (int i = threadIdx.x; i < 4096; i += 256) {
      int o = i >> 6, c = i & 63;
      Wt[m * 4096 + c * 64 + o] = src[i];
    }
  }
}

// ---------- conv table, both branches in one launch ----------
__global__ __launch_bounds__(192) void conv_table_kernel(
    const float* __restrict__ emb_en, const float* __restrict__ emb_pr,
    const float* __restrict__ W2en, const float* __restrict__ W2pr,
    float* __restrict__ Cen, float* __restrict__ Cpr) {
  int blk = blockIdx.x;
  int branch = (blk >= 513);
  const float* emb = branch ? emb_pr : emb_en;
  const float* W2 = branch ? W2pr : W2en;
  float* C = branch ? Cpr : Cen;
  int v0 = (branch ? blk - 513 : blk) * VT;
  __shared__ float e[VT][128];
  int t = threadIdx.x;
  int nv = 4097 - v0; if (nv > VT) nv = VT;
  for (int i = t; i < nv * 128; i += 192) e[i >> 7][i & 127] = emb[v0 * 128 + i];
  __syncthreads();
  float a0[VT], a1[VT], a2[VT];
#pragma unroll
  for (int v = 0; v < VT; ++v) { a0[v] = 0.f; a1[v] = 0.f; a2[v] = 0.f; }
  for (int ic = 0; ic < 128; ++ic) {
    float w0 = W2[ic * 576 + t];
    float w1 = W2[ic * 576 + t + 192];
    float w2 = W2[ic * 576 + t + 384];
#pragma unroll
    for (int v = 0; v < VT; ++v) {
      float ev = e[v][ic];
      a0[v] += ev * w0; a1[v] += ev * w1; a2[v] += ev * w2;
    }
  }
  for (int v = 0; v < nv; ++v) {
    C[(size_t)(v0 + v) * 576 + t] = a0[v];
    C[(size_t)(v0 + v) * 576 + t + 192] = a1[v];
    C[(size_t)(v0 + v) * 576 + t + 384] = a2[v];
  }
}

// ---------- frontend, both branches, 4 rows/block ----------
__global__ __launch_bounds__(256) void frontend_kernel(
    const int* __restrict__ en_ids, const int* __restrict__ pr_ids,
    const float* __restrict__ Cen, const float* __restrict__ Cpr,
    const float* __restrict__ cb_en, const float* __restrict__ cb_pr,
    const float* __restrict__ bn_en, const float* __restrict__ bn_pr,
    float* __restrict__ Xen, float* __restrict__ Xpr) {
  int t = threadIdx.x;
  int wid = t >> 6, oc = t & 63;
  int row = blockIdx.x * 4 + wid;
  int branch, b, s, S, lrow;
  row_decode(row, branch, b, s, S, lrow);
  const int* ids = branch ? pr_ids : en_ids;
  int Lin = branch ? LP_LEN : LE_LEN;
  const float* C = branch ? Cpr : Cen;
  const float* cb = branch ? cb_pr : cb_en;
  const float* bn = branch ? bn_pr : bn_en;
  float* X = branch ? Xpr : Xen;
  __shared__ int idl[4][28];
  if (oc < 28) idl[wid][oc] = ids[b * Lin + s * 20 + oc];
  __syncthreads();
  float bias = cb[oc];
  float m = -INFINITY;
  for (int p = 0; p < 20; ++p) {
    float acc = bias;
#pragma unroll
    for (int k = 0; k < 9; ++k) acc += C[idl[wid][p + k] * 576 + k * 64 + oc];
    acc = fmaxf(acc, 0.f);
    m = fmaxf(m, acc);
  }
  float g = bn[oc], be = bn[64 + oc], mu = bn[128 + oc], var = bn[192 + oc];
  X[(size_t)lrow * 64 + oc] = (m - mu) * rsqrtf(var + 1e-5f) * g + be;
}

// ---------- qkv + RoPE, both branches, 4 rows/block (2x ILP per output) ----------
__global__ __launch_bounds__(256) void qkv_rope_kernel(
    const float* __restrict__ Xen, const float* __restrict__ Xpr,
    const float* __restrict__ t_qkv_w, const float* __restrict__ t_qkv_b, int l,
    float* __restrict__ Q, float* __restrict__ K, float* __restrict__ V) {
  int t = threadIdx.x;
  int wid = t >> 6, oc = t & 63;
  int row = blockIdx.x * 4 + wid;
  int branch, b, s, S, lrow;
  row_decode(row, branch, b, s, S, lrow);
  const float* X = branch ? Xpr : Xen;
  int idx = branch * 2 + l;
  const float* W = t_qkv_w + (size_t)idx * 3 * 4096;
  const float* bias = t_qkv_b + idx * 192;
  __shared__ float xr[4][64], qs[4][64], ks[4][64];
  xr[wid][oc] = X[lrow * 64 + oc];
  __syncthreads();
  float q0 = bias[oc], k0 = bias[64 + oc], v0 = bias[128 + oc];
  float q1 = 0.f, k1 = 0.f, v1 = 0.f;
  for (int c = 0; c < 64; c += 2) {
    float xa = xr[wid][c], xb = xr[wid][c + 1];
    q0 += xa * W[c * 64 + oc];
    q1 += xb * W[(c + 1) * 64 + oc];
    k0 += xa * W[4096 + c * 64 + oc];
    k1 += xb * W[4096 + (c + 1) * 64 + oc];
    v0 += xa * W[8192 + c * 64 + oc];
    v1 += xb * W[8192 + (c + 1) * 64 + oc];
  }
  float q = q0 + q1, k = k0 + k1, v = v0 + v1;
  qs[wid][oc] = q; ks[wid][oc] = k;
  V[row * 64 + oc] = v;
  __syncthreads();
  int j = oc & 7;
  int p = j >> 1;
  float inv = powf(10000.f, -(float)p * 0.25f);
  float ang = (float)s * inv;
  float cc = cosf(ang), ss = sinf(ang);
  float qo, ko;
  if ((j & 1) == 0) {
    qo = qs[wid][oc] * cc - qs[wid][oc + 1] * ss;
    ko = ks[wid][oc] * cc - ks[wid][oc + 1] * ss;
  } else {
    qo = qs[wid][oc - 1] * ss + qs[wid][oc] * cc;
    ko = ks[wid][oc - 1] * ss + ks[wid][oc] * cc;
  }
  Q[row * 64 + oc] = qo;
  K[row * 64 + oc] = ko;
}

// ---------- attention, split-K (2 groups of 192), two sections per launch ----------
__global__ __launch_bounds__(384) void attn_kernel(
    const float* __restrict__ Q, const float* __restrict__ K,
    const float* __restrict__ V, float* __restrict__ ctx,
    int nblk0, int Sq0, int Sk0, int qb0, int kb0, float als0,
    int Sq1, int Sk1, int qb1, int kb1, float als1,
    float* __restrict__ aloss_acc) {
  int blk = blockIdx.x;
  int bh, Sq, Sk, qb, kb; float als;
  if (blk < nblk0) { bh = blk; Sq = Sq0; Sk = Sk0; qb = qb0; kb = kb0; als = als0; }
  else { bh = blk - nblk0; Sq = Sq1; Sk = Sk1; qb = qb1; kb = kb1; als = als1; }
  int b = bh >> 3, h = bh & 7;
  __shared__ float kk[160 * 8], vv[160 * 8];
  __shared__ float pm[192], psum[192], psum2[192], pacc[192][8];
  int t = threadIdx.x;
  int g = t / 192, tq = t - g * 192;
  for (int i = t; i < Sk * 8; i += 384) {
    int r = i >> 3, j = i & 7;
    kk[i] = K[(size_t)(kb + b * Sk + r) * 64 + h * 8 + j];
    vv[i] = V[(size_t)(kb + b * Sk + r) * 64 + h * 8 + j];
  }
  __syncthreads();
  int half = (Sk + 1) >> 1;
  int kbeg = g ? half : 0;
  int kend = g ? Sk : half;
  float m = -INFINITY, sum = 0.f, sum2 = 0.f, acc[8];
#pragma unroll
  for (int j = 0; j < 8; ++j) acc[j] = 0.f;
  if (tq < Sq) {
    float q[8];
#pragma unroll
    for (int j = 0; j < 8; ++j) q[j] = Q[(size_t)(qb + b * Sq + tq) * 64 + h * 8 + j];
    const float sc = 0.35355339059327373f;
    for (int kki = kbeg; kki < kend; ++kki) {
      float sdot = 0.f;
#pragma unroll
      for (int j = 0; j < 8; ++j) sdot += q[j] * kk[kki * 8 + j];
      sdot *= sc;
      if (sdot > m) {
        float f = __expf(m - sdot);
        sum *= f; sum2 *= f * f;
#pragma unroll
        for (int j = 0; j < 8; ++j) acc[j] *= f;
        m = sdot;
      }
      float e = __expf(sdot - m);
      sum += e; sum2 += e * e;
#pragma unroll
      for (int j = 0; j < 8; ++j) acc[j] += e * vv[kki * 8 + j];
    }
  }
  if (g == 1 && tq < Sq) {
    pm[tq] = m; psum[tq] = sum; psum2[tq] = sum2;
#pragma unroll
    for (int j = 0; j < 8; ++j) pacc[tq][j] = acc[j];
  }
  __syncthreads();
  float rowsum2 = 0.f;
  if (g == 0 && tq < Sq) {
    float m1 = pm[tq];
    float mf = fmaxf(m, m1);
    float f0 = __expf(m - mf), f1 = __expf(m1 - mf);
    float sumf = sum * f0 + psum[tq] * f1;
    float invs = 1.f / sumf;
#pragma unroll
    for (int j = 0; j < 8; ++j) {
      float a = acc[j] * f0 + pacc[tq][j] * f1;
      ctx[(size_t)(qb + b * Sq + tq) * 64 + h * 8 + j] = a * invs;
    }
    rowsum2 = (sum2 * f0 * f0 + psum2[tq] * f1 * f1) * invs * invs;
  }
  if (als != 0.f) {
    float wsum = rowsum2;
    for (int off = 32; off; off >>= 1) wsum += __shfl_down(wsum, off, 64);
    __shared__ float wred[6];
    if ((t & 63) == 0) wred[t >> 6] = wsum;
    __syncthreads();
    if (t == 0) {
      float tot = wred[0] + wred[1] + wred[2] + wred[3] + wred[4] + wred[5];
      atomicAdd(aloss_acc, tot * als);
    }
  }
}

// ---------- channel attention, both branches (grid 64) ----------
__global__ __launch_bounds__(512) void ca_kernel(
    const float* __restrict__ ctx, const float* __restrict__ t_ca_w1,
    const float* __restrict__ t_ca_w2, int l, float* __restrict__ ca) {
  int bp = blockIdx.x;  // 0..63
  int branch = bp >> 5, b = bp & 31;
  int S = branch ? SP : SE;
  int base = branch ? ROWS_EN : 0;
  int idx = branch * 2 + l;
  const float* W1 = t_ca_w1 + idx * 512;
  const float* W2 = t_ca_w2 + idx * 512;
  int t = threadIdx.x;  // 512
  int c = t & 63, seg = t >> 6;
  float sum = 0.f, mx = -INFINITY;
  for (int s = seg; s < S; s += 8) {
    float v = ctx[(size_t)(base + b * S + s) * 64 + c];
    sum += v; mx = fmaxf(mx, v);
  }
  __shared__ float ssum[8][64], smx[8][64];
  ssum[seg][c] = sum; smx[seg][c] = mx;
  __syncthreads();
  __shared__ float avg_l[64], mx_l[64], ha[8], hm[8];
  if (t < 64) {
    float a = 0.f, m = -INFINITY;
#pragma unroll
    for (int g = 0; g < 8; ++g) { a += ssum[g][t]; m = fmaxf(m, smx[g][t]); }
    avg_l[t] = a / (float)S; mx_l[t] = m;
  }
  __syncthreads();
  if (t < 8) {
    float a = 0.f, m2 = 0.f;
    for (int i = 0; i < 64; ++i) {
      a += avg_l[i] * W1[i * 8 + t];
      m2 += mx_l[i] * W1[i * 8 + t];
    }
    ha[t] = fmaxf(a, 0.f); hm[t] = fmaxf(m2, 0.f);
  }
  __syncthreads();
  if (t < 64) {
    float o = 0.f;
#pragma unroll
    for (int j = 0; j < 8; ++j) o += (ha[j] + hm[j]) * W2[j * 64 + t];
    ca[bp * 64 + t] = 1.f / (1.f + expf(-o));
  }
}

// ---------- apply ca + spatial feat, both branches ----------
__global__ __launch_bounds__(256) void feat_kernel(
    float* __restrict__ ctx, const float* __restrict__ ca,
    float* __restrict__ fmean, float* __restrict__ fmax) {
  int row = blockIdx.x * 4 + (threadIdx.x >> 6);
  int branch, b, s, S, lrow;
  row_decode(row, branch, b, s, S, lrow);
  int c = threadIdx.x & 63;
  float v = ctx[row * 64 + c] * ca[(branch * 32 + b) * 64 + c];
  ctx[row * 64 + c] = v;
  float sum = v, mx = v;
  for (int off = 32; off; off >>= 1) {
    sum += __shfl_xor(sum, off, 64);
    mx = fmaxf(mx, __shfl_xor(mx, off, 64));
  }
  if (c == 0) { fmean[row] = sum * (1.f / 64.f); fmax[row] = mx; }
}

// ---------- fused tail: sa + out proj + LN1 + FFN + LN2, 4 rows/block ----------
__global__ __launch_bounds__(256) void tail_kernel(
    const float* __restrict__ ctx, const float* __restrict__ fmean,
    const float* __restrict__ fmax, const float* __restrict__ t_sa_w,
    const float* __restrict__ t_o_w, const float* __restrict__ t_o_b,
    const float* __restrict__ t_ln1, const float* __restrict__ t_ff1_w,
    const float* __restrict__ t_ff1_b, const float* __restrict__ t_ff2_w,
    const float* __restrict__ t_ff2_b, const float* __restrict__ t_ln2,
    int l, float* __restrict__ Xen, float* __restrict__ Xpr) {
  int t = threadIdx.x;
  int wid = t >> 6, lane = t & 63;
  int row = blockIdx.x * 4 + wid;
  int branch, b, s, S, lrow;
  row_decode(row, branch, b, s, S, lrow);
  int idx = branch * 2 + l;
  const float* sa_w = t_sa_w + idx * 14;
  float sa = 0.f;
  if (lane == 0) {
    for (int k = 0; k < 7; ++k) {
      int p = s + k - 3;
      if (p >= 0 && p < S)
        sa += fmean[row - s + p] * sa_w[k] + fmax[row - s + p] * sa_w[7 + k];
    }
    sa = 1.f / (1.f + expf(-sa));
  }
  sa = __shfl(sa, 0, 64);
  __shared__ float rowv[4][64], xr[4][64], h[4][256];
  rowv[wid][lane] = ctx[row * 64 + lane] * sa;
  __syncthreads();
  const float* o_w = t_o_w + (size_t)idx * 4096;
  float p0 = t_o_b[idx * 64 + lane], p1 = 0.f, p2 = 0.f, p3 = 0.f;
  for (int c = 0; c < 64; c += 4) {
    p0 += rowv[wid][c] * o_w[c * 64 + lane];
    p1 += rowv[wid][c + 1] * o_w[(c + 1) * 64 + lane];
    p2 += rowv[wid][c + 2] * o_w[(c + 2) * 64 + lane];
    p3 += rowv[wid][c + 3] * o_w[(c + 3) * 64 + lane];
  }
  float o = (p0 + p1) + (p2 + p3);
  float* X = branch ? Xpr : Xen;
  float r = X[lrow * 64 + lane] + o;
  float mu = r;
  for (int of = 32; of; of >>= 1) mu += __shfl_xor(mu, of, 64);
  mu *= (1.f / 64.f);
  float d = r - mu;
  float var = d * d;
  for (int of = 32; of; of >>= 1) var += __shfl_xor(var, of, 64);
  var *= (1.f / 64.f);
  const float* ln1 = t_ln1 + idx * 128;
  float x1 = d * rsqrtf(var + 1e-5f) * ln1[lane] + ln1[64 + lane];
  xr[wid][lane] = x1;
  __syncthreads();
  const float* W1 = t_ff1_w + (size_t)idx * 16384;
  float a0 = t_ff1_b[idx * 256 + t], a1 = a0, a2 = a0, a3 = a0;
  for (int c = 0; c < 64; ++c) {
    float w = W1[c * 256 + t];
    a0 += xr[0][c] * w; a1 += xr[1][c] * w; a2 += xr[2][c] * w; a3 += xr[3][c] * w;
  }
  h[0][t] = fmaxf(a0, 0.f); h[1][t] = fmaxf(a1, 0.f);
  h[2][t] = fmaxf(a2, 0.f); h[3][t] = fmaxf(a3, 0.f);
  __syncthreads();
  const float* W2 = t_ff2_w + (size_t)idx * 16384;
  float q0 = t_ff2_b[idx * 64 + lane], q1 = 0.f, q2 = 0.f, q3 = 0.f;
  for (int j = 0; j < 256; j += 4) {
    q0 += h[wid][j] * W2[j * 64 + lane];
    q1 += h[wid][j + 1] * W2[(j + 1) * 64 + lane];
    q2 += h[wid][j + 2] * W2[(j + 2) * 64 + lane];
    q3 += h[wid][j + 3] * W2[(j + 3) * 64 + lane];
  }
  float o2 = (q0 + q1) + (q2 + q3);
  float r2 = x1 + o2;
  mu = r2;
  for (int of = 32; of; of >>= 1) mu += __shfl_xor(mu, of, 64);
  mu *= (1.f / 64.f);
  d = r2 - mu;
  var = d * d;
  for (int of = 32; of; of >>= 1) var += __shfl_xor(var, of, 64);
  var *= (1.f / 64.f);
  const float* ln2 = t_ln2 + idx * 128;
  X[lrow * 64 + lane] = d * rsqrtf(var + 1e-5f) * ln2[lane] + ln2[64 + lane];
}

// ---------- cross projections: Q(en) + K,V(pr) in one launch (ILP) ----------
__global__ __launch_bounds__(256) void cross_proj_kernel(
    const float* __restrict__ Xen, const float* __restrict__ Xpr,
    const float* __restrict__ Wt, const float* __restrict__ bias,
    float* __restrict__ Q, float* __restrict__ K, float* __restrict__ V) {
  int t = threadIdx.x;
  int wid = t >> 6, oc = t & 63;
  int blk = blockIdx.x;
  __shared__ float xr[4][64];
  if (blk < ROWS_EN / 4) {
    int row = blk * 4 + wid;
    xr[wid][oc] = Xen[row * 64 + oc];
    __syncthreads();
    float p0 = bias[oc], p1 = 0.f, p2 = 0.f, p3 = 0.f;
    for (int c = 0; c < 64; c += 4) {
      p0 += xr[wid][c] * Wt[c * 64 + oc];
      p1 += xr[wid][c + 1] * Wt[(c + 1) * 64 + oc];
      p2 += xr[wid][c + 2] * Wt[(c + 2) * 64 + oc];
      p3 += xr[wid][c + 3] * Wt[(c + 3) * 64 + oc];
    }
    Q[row * 64 + oc] = (p0 + p1) + (p2 + p3);
  } else {
    int lr = (blk - ROWS_EN / 4) * 4 + wid;
    xr[wid][oc] = Xpr[lr * 64 + oc];
    __syncthreads();
    float k0 = bias[64 + oc], k1 = 0.f, v0 = bias[128 + oc], v1 = 0.f;
    for (int c = 0; c < 64; c += 2) {
      float xa = xr[wid][c], xb = xr[wid][c + 1];
      k0 += xa * Wt[4096 + c * 64 + oc];
      k1 += xb * Wt[4096 + (c + 1) * 64 + oc];
      v0 += xa * Wt[8192 + c * 64 + oc];
      v1 += xb * Wt[8192 + (c + 1) * 64 + oc];
    }
    K[(ROWS_EN + lr) * 64 + oc] = k0 + k1;
    V[(ROWS_EN + lr) * 64 + oc] = v0 + v1;
  }
}

// ---------- self QKV for en(AttEn) + pr(Xpr) in one launch (2x ILP) ----------
__global__ __launch_bounds__(256) void self_qkv_kernel(
    const float* __restrict__ inEn, const float* __restrict__ inPr,
    const float* __restrict__ Wt, const float* __restrict__ bias,
    float* __restrict__ Q, float* __restrict__ K, float* __restrict__ V) {
  int t = threadIdx.x;
  int wid = t >> 6, oc = t & 63;
  int row = blockIdx.x * 4 + wid;
  const float* in; int lrow;
  if (row < ROWS_EN) { in = inEn; lrow = row; }
  else { in = inPr; lrow = row - ROWS_EN; }
  __shared__ float xr[4][64];
  xr[wid][oc] = in[lrow * 64 + oc];
  __syncthreads();
  float q0 = bias[oc], k0 = bias[64 + oc], v0 = bias[128 + oc];
  float q1 = 0.f, k1 = 0.f, v1 = 0.f;
  for (int c = 0; c < 64; c += 2) {
    float xa = xr[wid][c], xb = xr[wid][c + 1];
    q0 += xa * Wt[c * 64 + oc];
    q1 += xb * Wt[(c + 1) * 64 + oc];
    k0 += xa * Wt[4096 + c * 64 + oc];
    k1 += xb * Wt[4096 + (c + 1) * 64 + oc];
    v0 += xa * Wt[8192 + c * 64 + oc];
    v1 += xb * Wt[8192 + (c + 1) * 64 + oc];
  }
  Q[row * 64 + oc] = q0 + q1;
  K[row * 64 + oc] = k0 + k1;
  V[row * 64 + oc] = v0 + v1;
}

// ---------- out projection, en->out0, pr->out1 (4-acc ILP) ----------
__global__ __launch_bounds__(256) void dual_proj_kernel(
    const float* __restrict__ in, const float* __restrict__ Wt,
    const float* __restrict__ bias, float* __restrict__ out0,
    float* __restrict__ out1) {
  int t = threadIdx.x;
  int wid = t >> 6, oc = t & 63;
  int row = blockIdx.x * 4 + wid;
  float* out; int lrow;
  if (row < ROWS_EN) { out = out0; lrow = row; }
  else { out = out1; lrow = row - ROWS_EN; }
  __shared__ float xr[4][64];
  xr[wid][oc] = in[row * 64 + oc];
  __syncthreads();
  float p0 = bias[oc], p1 = 0.f, p2 = 0.f, p3 = 0.f;
  for (int c = 0; c < 64; c += 4) {
    p0 += xr[wid][c] * Wt[c * 64 + oc];
    p1 += xr[wid][c + 1] * Wt[(c + 1) * 64 + oc];
    p2 += xr[wid][c + 2] * Wt[(c + 2) * 64 + oc];
    p3 += xr[wid][c + 3] * Wt[(c + 3) * 64 + oc];
  }
  out[lrow * 64 + oc] = (p0 + p1) + (p2 + p3);
}

// ---------- mean over sequence -> combined + fourier trig table ----------
__global__ __launch_bounds__(512) void mean_trig_kernel(
    const float* __restrict__ en_fin, const float* __restrict__ pr_fin,
    float* __restrict__ comb, float* __restrict__ trig) {
  int b = blockIdx.x;
  int t = threadIdx.x;
  int col = t & 127, seg = t >> 7;
  float sum = 0.f;
  if (col < 64) {
    for (int s = seg; s < SE; s += 4) sum += en_fin[(b * SE + s) * 64 + col];
  } else {
    int c = col - 64;
    for (int s = seg; s < SP; s += 4) sum += pr_fin[(b * SP + s) * 64 + c];
  }
  __shared__ float red[4][128];
  __shared__ float comb_s[128];
  red[seg][col] = sum;
  __syncthreads();
  if (t < 128) {
    float tot = red[0][t] + red[1][t] + red[2][t] + red[3][t];
    float cv = tot / (t < 64 ? (float)SE : (float)SP);
    comb_s[t] = cv;
    comb[b * 128 + t] = cv;
  }
  __syncthreads();
  for (int i = t; i < 640; i += 512) {
    int ii = i / 5, g = i - ii * 5;
    float x = comb_s[ii] * (float)(g + 1);
    trig[b * 1280 + i] = cosf(x);
    trig[b * 1280 + 640 + i] = sinf(x);
  }
}

// ---------- fourier layer 1 (pure dot over precomputed trig) ----------
__global__ __launch_bounds__(256) void fourier1_kernel(
    const float* __restrict__ trig, const float* __restrict__ wc,
    const float* __restrict__ ws, const float* __restrict__ bias,
    float* __restrict__ hidden) {
  int b = blockIdx.x;
  int t = threadIdx.x;
  int wid = t >> 6, lane = t & 63;
  int o = blockIdx.y * 4 + wid;
  if (o >= 257) return;
  const float* ct = trig + b * 1280;
  const float* st = ct + 640;
  float acc = 0.f;
  for (int i = lane; i < 640; i += 64)
    acc += ct[i] * wc[(size_t)o * 640 + i] + st[i] * ws[(size_t)o * 640 + i];
  for (int off = 32; off; off >>= 1) acc += __shfl_xor(acc, off, 64);
  if (lane == 0) hidden[b * 257 + o] = acc + bias[o];
}

// ---------- fourier layer 2 + sigmoid + aloss writeout ----------
__global__ void fourier2_kernel(const float* __restrict__ hidden,
                                const float* __restrict__ wc,
                                const float* __restrict__ ws,
                                const float* __restrict__ bias,
                                const float* __restrict__ aloss_acc,
                                float* __restrict__ out) {
  int b = blockIdx.x;
  int t = threadIdx.x;  // 320
  float acc = 0.f;
  if (t < 257) {
    float x = hidden[b * 257 + t];
#pragma unroll
    for (int g = 0; g < 5; ++g) {
      float a = x * (float)(g + 1);
      acc += cosf(a) * wc[t * 5 + g] + sinf(a) * ws[t * 5 + g];
    }
  }
  for (int off = 32; off; off >>= 1) acc += __shfl_xor(acc, off, 64);
  __shared__ float wred[5];
  if ((t & 63) == 0) wred[t >> 6] = acc;
  __syncthreads();
  if (t == 0) {
    float tot = wred[0] + wred[1] + wred[2] + wred[3] + wred[4] + bias[0];
    out[b] = 1.f / (1.f + expf(-tot));
    if (b == 0) out[4128] = aloss_acc[0];
  }
}

extern "C" void kernel_launch(void* const* d_in, const int* in_sizes, int n_in,
                              void* d_out, int out_size, void* d_ws, size_t ws_size,
                              hipStream_t stream) {
  const int* en_ids = (const int*)d_in[0];
  const int* pr_ids = (const int*)d_in[1];
  const float* emb_en = (const float*)d_in[4];
  const float* emb_pr = (const float*)d_in[5];
  const float* conv_w_en = (const float*)d_in[6];
  const float* conv_b_en = (const float*)d_in[7];
  const float* conv_w_pr = (const float*)d_in[8];
  const float* conv_b_pr = (const float*)d_in[9];
  const float* bn_en = (const float*)d_in[10];
  const float* bn_pr = (const float*)d_in[11];
  const float* t_qkv_w = (const float*)d_in[12];
  const float* t_qkv_b = (const float*)d_in[13];
  const float* t_o_w = (const float*)d_in[14];
  const float* t_o_b = (const float*)d_in[15];
  const float* t_ca_w1 = (const float*)d_in[16];
  const float* t_ca_w2 = (const float*)d_in[17];
  const float* t_sa_w = (const float*)d_in[18];
  const float* t_ff1_w = (const float*)d_in[19];
  const float* t_ff1_b = (const float*)d_in[20];
  const float* t_ff2_w = (const float*)d_in[21];
  const float* t_ff2_b = (const float*)d_in[22];
  const float* t_ln1 = (const float*)d_in[23];
  const float* t_ln2 = (const float*)d_in[24];
  const float* cross_in_w = (const float*)d_in[25];
  const float* cross_in_b = (const float*)d_in[26];
  const float* cross_out_w = (const float*)d_in[27];
  const float* cross_out_b = (const float*)d_in[28];
  const float* self_in_w = (const float*)d_in[29];
  const float* self_in_b = (const float*)d_in[30];
  const float* self_out_w = (const float*)d_in[31];
  const float* self_out_b = (const float*)d_in[32];
  const float* fk1_c = (const float*)d_in[33];
  const float* fk1_s = (const float*)d_in[34];
  const float* fk1_b = (const float*)d_in[35];
  const float* fk2_c = (const float*)d_in[36];
  const float* fk2_s = (const float*)d_in[37];
  const float* fk2_b = (const float*)d_in[38];

  float* out = (float*)d_out;
  float* ws = (float*)d_ws;
  size_t off = 0;
  float* Cen = ws + off;  off += (size_t)4097 * 576;
  float* Cpr = ws + off;  off += (size_t)4097 * 576;
  float* W2en = ws + off; off += 73728;
  float* W2pr = ws + off; off += 73728;
  float* Wt = ws + off;   off += 8 * 4096;
  float* Xen = ws + off;  off += (size_t)ROWS_EN * 64;
  float* Xpr = ws + off;  off += (size_t)ROWS_PR * 64;
  float* Qb = ws + off;   off += (size_t)ROWS_ALL * 64;
  float* Kb = ws + off;   off += (size_t)ROWS_ALL * 64;
  float* Vb = ws + off;   off += (size_t)ROWS_ALL * 64;
  float* Ctx = ws + off;  off += (size_t)ROWS_ALL * 64;
  float* AttEn = ws + off; off += (size_t)ROWS_EN * 64;
  float* PrFin = ws + off; off += (size_t)ROWS_PR * 64;
  float* Fm = ws + off;   off += ROWS_ALL;
  float* Fx = ws + off;   off += ROWS_ALL;
  float* CaB = ws + off;  off += 2 * BB * 64;
  float* Hid = ws + off;  off += BB * 257;
  float* Trig = ws + off; off += (size_t)BB * 1280;
  float* Al = ws + off;   off += 8;

  const float als_en = 1.f / ((float)BB * 8.f * (float)SE * (float)SE);
  const float als_pr = 1.f / ((float)BB * 8.f * (float)SP * (float)SP);

  // setup: transposes + Al zero
  prep_kernel<<<584, 256, 0, stream>>>(conv_w_en, conv_w_pr, cross_in_w,
                                       cross_out_w, self_in_w, self_out_w,
                                       W2en, W2pr, Wt, Al);
  // frontend (both branches)
  conv_table_kernel<<<1026, 192, 0, stream>>>(emb_en, emb_pr, W2en, W2pr, Cen, Cpr);
  frontend_kernel<<<ROWS_ALL / 4, 256, 0, stream>>>(en_ids, pr_ids, Cen, Cpr,
                                                    conv_b_en, conv_b_pr, bn_en,
                                                    bn_pr, Xen, Xpr);

  // transformer layers (both branches per launch)
  for (int l = 0; l < 2; ++l) {
    qkv_rope_kernel<<<ROWS_ALL / 4, 256, 0, stream>>>(Xen, Xpr, t_qkv_w,
                                                      t_qkv_b, l, Qb, Kb, Vb);
    attn_kernel<<<512, 384, 0, stream>>>(Qb, Kb, Vb, Ctx,
                                         256, SE, SE, 0, 0, als_en,
                                         SP, SP, ROWS_EN, ROWS_EN, als_pr, Al);
    ca_kernel<<<64, 512, 0, stream>>>(Ctx, t_ca_w1, t_ca_w2, l, CaB);
    feat_kernel<<<ROWS_ALL / 4, 256, 0, stream>>>(Ctx, CaB, Fm, Fx);
    tail_kernel<<<ROWS_ALL / 4, 256, 0, stream>>>(
        Ctx, Fm, Fx, t_sa_w, t_o_w, t_o_b, t_ln1, t_ff1_w, t_ff1_b,
        t_ff2_w, t_ff2_b, t_ln2, l, Xen, Xpr);
  }

  // cross attention: en_att = mha(en, pr, pr)
  cross_proj_kernel<<<ROWS_ALL / 4, 256, 0, stream>>>(Xen, Xpr, Wt,
                                                      cross_in_b, Qb, Kb, Vb);
  attn_kernel<<<256, 384, 0, stream>>>(Qb, Kb, Vb, Ctx,
                                       256, SE, SP, 0, ROWS_EN, 0.f,
                                       0, 0, 0, 0, 0.f, Al);
  dual_proj_kernel<<<ROWS_EN / 4, 256, 0, stream>>>(Ctx, Wt + 3 * 4096,
                                                    cross_out_b, AttEn, AttEn);

  // self attention: en(AttEn) and pr(Xpr) merged
  self_qkv_kernel<<<ROWS_ALL / 4, 256, 0, stream>>>(AttEn, Xpr, Wt + 4 * 4096,
                                                    self_in_b, Qb, Kb, Vb);
  attn_kernel<<<512, 384, 0, stream>>>(Qb, Kb, Vb, Ctx,
                                       256, SE, SE, 0, 0, 0.f,
                                       SP, SP, ROWS_EN, ROWS_EN, 0.f, Al);
  dual_proj_kernel<<<ROWS_ALL / 4, 256, 0, stream>>>(Ctx, Wt + 7 * 4096,
                                                     self_out_b, Xen, PrFin);

  // combined + fourier head
  mean_trig_kernel<<<BB, 512, 0, stream>>>(Xen, PrFin, out + 32, Trig);
  fourier1_kernel<<<dim3(BB, 65), 256, 0, stream>>>(Trig, fk1_c, fk1_s,
                                                    fk1_b, Hid);
  fourier2_kernel<<<BB, 320, 0, stream>>>(Hid, fk2_c, fk2_s, fk2_b, Al, out);
}

// Round 15
// 313.221 us; speedup vs baseline: 1.6960x; 1.0384x over previous
//
#include <hip/hip_runtime.h>
#include <math.h>

#define BB 32
#define SE 149
#define SP 99
#define LE_LEN 3000
#define LP_LEN 2000
#define VT 8
#define ROWS_EN (BB * SE)          // 4768
#define ROWS_PR (BB * SP)          // 3168
#define ROWS_ALL (ROWS_EN + ROWS_PR)  // 7936

__device__ __forceinline__ void row_decode(int row, int& branch, int& b,
                                           int& s, int& S, int& lrow) {
  if (row < ROWS_EN) { branch = 0; S = SE; lrow = row; b = row / SE; s = row - b * SE; }
  else { branch = 1; S = SP; lrow = row - ROWS_EN; b = lrow / SP; s = lrow - b * SP; }
}

// ---------- prep: conv_w transposes (en+pr), proj transposes, Al zero ----------
__global__ __launch_bounds__(256) void prep_kernel(
    const float* __restrict__ cw_en, const float* __restrict__ cw_pr,
    const float* __restrict__ cross_in, const float* __restrict__ cross_out,
    const float* __restrict__ self_in, const float* __restrict__ self_out,
    float* __restrict__ W2en, float* __restrict__ W2pr,
    float* __restrict__ Wt, float* __restrict__ Al) {
  int bb = blockIdx.x;
  if (bb == 0 && threadIdx.x == 0) Al[0] = 0.f;
  if (bb < 576) {
    const float* src = (bb < 288) ? cw_en : cw_pr;
    float* dst = (bb < 288) ? W2en : W2pr;
    int i = ((bb < 288) ? bb : bb - 288) * 256 + threadIdx.x;
    int oc = i / 1152, r = i % 1152, ic = r / 9, k = r % 9;
    dst[ic * 576 + k * 64 + oc] = src[i];
  } else {
    int m = bb - 576;  // 0..7
    const float* src = (m < 3) ? cross_in + m * 4096
                     : (m == 3) ? cross_out
                     : (m < 7) ? self_in + (m - 4) * 4096
                     : self_out;
    for (int i = threadIdx.x; i < 4096; i += 256) {
      int o = i >> 6, c = i & 63;
      Wt[m * 4096 + c * 64 + o] = src[i];
    }
  }
}

// ---------- conv table, both branches in one launch ----------
__global__ __launch_bounds__(192) void conv_table_kernel(
    const float* __restrict__ emb_en, const float* __restrict__ emb_pr,
    const float* __restrict__ W2en, const float* __restrict__ W2pr,
    float* __restrict__ Cen, float* __restrict__ Cpr) {
  int blk = blockIdx.x;
  int branch = (blk >= 513);
  const float* emb = branch ? emb_pr : emb_en;
  const float* W2 = branch ? W2pr : W2en;
  float* C = branch ? Cpr : Cen;
  int v0 = (branch ? blk - 513 : blk) * VT;
  __shared__ float e[VT][128];
  int t = threadIdx.x;
  int nv = 4097 - v0; if (nv > VT) nv = VT;
  for (int i = t; i < nv * 128; i += 192) e[i >> 7][i & 127] = emb[v0 * 128 + i];
  __syncthreads();
  float a0[VT], a1[VT], a2[VT];
#pragma unroll
  for (int v = 0; v < VT; ++v) { a0[v] = 0.f; a1[v] = 0.f; a2[v] = 0.f; }
  for (int ic = 0; ic < 128; ++ic) {
    float w0 = W2[ic * 576 + t];
    float w1 = W2[ic * 576 + t + 192];
    float w2 = W2[ic * 576 + t + 384];
#pragma unroll
    for (int v = 0; v < VT; ++v) {
      float ev = e[v][ic];
      a0[v] += ev * w0; a1[v] += ev * w1; a2[v] += ev * w2;
    }
  }
  for (int v = 0; v < nv; ++v) {
    C[(size_t)(v0 + v) * 576 + t] = a0[v];
    C[(size_t)(v0 + v) * 576 + t + 192] = a1[v];
    C[(size_t)(v0 + v) * 576 + t + 384] = a2[v];
  }
}

// ---------- frontend, both branches, 4 rows/block ----------
__global__ __launch_bounds__(256) void frontend_kernel(
    const int* __restrict__ en_ids, const int* __restrict__ pr_ids,
    const float* __restrict__ Cen, const float* __restrict__ Cpr,
    const float* __restrict__ cb_en, const float* __restrict__ cb_pr,
    const float* __restrict__ bn_en, const float* __restrict__ bn_pr,
    float* __restrict__ Xen, float* __restrict__ Xpr) {
  int t = threadIdx.x;
  int wid = t >> 6, oc = t & 63;
  int row = blockIdx.x * 4 + wid;
  int branch, b, s, S, lrow;
  row_decode(row, branch, b, s, S, lrow);
  const int* ids = branch ? pr_ids : en_ids;
  int Lin = branch ? LP_LEN : LE_LEN;
  const float* C = branch ? Cpr : Cen;
  const float* cb = branch ? cb_pr : cb_en;
  const float* bn = branch ? bn_pr : bn_en;
  float* X = branch ? Xpr : Xen;
  __shared__ int idl[4][28];
  if (oc < 28) idl[wid][oc] = ids[b * Lin + s * 20 + oc];
  __syncthreads();
  float bias = cb[oc];
  float m = -INFINITY;
  for (int p = 0; p < 20; ++p) {
    float acc = bias;
#pragma unroll
    for (int k = 0; k < 9; ++k) acc += C[idl[wid][p + k] * 576 + k * 64 + oc];
    acc = fmaxf(acc, 0.f);
    m = fmaxf(m, acc);
  }
  float g = bn[oc], be = bn[64 + oc], mu = bn[128 + oc], var = bn[192 + oc];
  X[(size_t)lrow * 64 + oc] = (m - mu) * rsqrtf(var + 1e-5f) * g + be;
}

// ---------- qkv + RoPE, both branches, 4 rows/block (2x ILP per output) ----------
__global__ __launch_bounds__(256) void qkv_rope_kernel(
    const float* __restrict__ Xen, const float* __restrict__ Xpr,
    const float* __restrict__ t_qkv_w, const float* __restrict__ t_qkv_b, int l,
    float* __restrict__ Q, float* __restrict__ K, float* __restrict__ V) {
  int t = threadIdx.x;
  int wid = t >> 6, oc = t & 63;
  int row = blockIdx.x * 4 + wid;
  int branch, b, s, S, lrow;
  row_decode(row, branch, b, s, S, lrow);
  const float* X = branch ? Xpr : Xen;
  int idx = branch * 2 + l;
  const float* W = t_qkv_w + (size_t)idx * 3 * 4096;
  const float* bias = t_qkv_b + idx * 192;
  __shared__ float xr[4][64], qs[4][64], ks[4][64];
  xr[wid][oc] = X[lrow * 64 + oc];
  __syncthreads();
  float q0 = bias[oc], k0 = bias[64 + oc], v0 = bias[128 + oc];
  float q1 = 0.f, k1 = 0.f, v1 = 0.f;
  for (int c = 0; c < 64; c += 2) {
    float xa = xr[wid][c], xb = xr[wid][c + 1];
    q0 += xa * W[c * 64 + oc];
    q1 += xb * W[(c + 1) * 64 + oc];
    k0 += xa * W[4096 + c * 64 + oc];
    k1 += xb * W[4096 + (c + 1) * 64 + oc];
    v0 += xa * W[8192 + c * 64 + oc];
    v1 += xb * W[8192 + (c + 1) * 64 + oc];
  }
  float q = q0 + q1, k = k0 + k1, v = v0 + v1;
  qs[wid][oc] = q; ks[wid][oc] = k;
  V[row * 64 + oc] = v;
  __syncthreads();
  int j = oc & 7;
  int p = j >> 1;
  float inv = powf(10000.f, -(float)p * 0.25f);
  float ang = (float)s * inv;
  float cc = cosf(ang), ss = sinf(ang);
  float qo, ko;
  if ((j & 1) == 0) {
    qo = qs[wid][oc] * cc - qs[wid][oc + 1] * ss;
    ko = ks[wid][oc] * cc - ks[wid][oc + 1] * ss;
  } else {
    qo = qs[wid][oc - 1] * ss + qs[wid][oc] * cc;
    ko = ks[wid][oc - 1] * ss + ks[wid][oc] * cc;
  }
  Q[row * 64 + oc] = qo;
  K[row * 64 + oc] = ko;
}

// ---------- attention, 4-way split-K (4 groups of 160), two sections ----------
__global__ __launch_bounds__(640) void attn_kernel(
    const float* __restrict__ Q, const float* __restrict__ K,
    const float* __restrict__ V, float* __restrict__ ctx,
    int nblk0, int Sq0, int Sk0, int qb0, int kb0, float als0,
    int Sq1, int Sk1, int qb1, int kb1, float als1,
    float* __restrict__ aloss_acc) {
  int blk = blockIdx.x;
  int bh, Sq, Sk, qb, kb; float als;
  if (blk < nblk0) { bh = blk; Sq = Sq0; Sk = Sk0; qb = qb0; kb = kb0; als = als0; }
  else { bh = blk - nblk0; Sq = Sq1; Sk = Sk1; qb = qb1; kb = kb1; als = als1; }
  int b = bh >> 3, h = bh & 7;
  __shared__ float kk[160 * 8], vv[160 * 8];
  __shared__ float pm[3][160], psum[3][160], psum2[3][160], pacc[3][160][8];
  int t = threadIdx.x;
  int g = t / 160, tq = t - g * 160;
  // float4 staging: each K/V row = 2 float4s
  for (int i = t; i < Sk * 2; i += 640) {
    int r = i >> 1, j = i & 1;
    const float4* ksrc = (const float4*)(K + (size_t)(kb + b * Sk + r) * 64 + h * 8);
    const float4* vsrc = (const float4*)(V + (size_t)(kb + b * Sk + r) * 64 + h * 8);
    ((float4*)kk)[i] = ksrc[j];
    ((float4*)vv)[i] = vsrc[j];
  }
  __syncthreads();
  int quarter = (Sk + 3) >> 2;
  int kbeg = g * quarter;
  int kend = kbeg + quarter; if (kend > Sk) kend = Sk;
  float m = -INFINITY, sum = 0.f, sum2 = 0.f, acc[8];
#pragma unroll
  for (int j = 0; j < 8; ++j) acc[j] = 0.f;
  if (tq < Sq) {
    float q[8];
#pragma unroll
    for (int j = 0; j < 8; ++j) q[j] = Q[(size_t)(qb + b * Sq + tq) * 64 + h * 8 + j];
    const float sc = 0.35355339059327373f;
    for (int kki = kbeg; kki < kend; ++kki) {
      float sdot = 0.f;
#pragma unroll
      for (int j = 0; j < 8; ++j) sdot += q[j] * kk[kki * 8 + j];
      sdot *= sc;
      if (sdot > m) {
        float f = __expf(m - sdot);
        sum *= f; sum2 *= f * f;
#pragma unroll
        for (int j = 0; j < 8; ++j) acc[j] *= f;
        m = sdot;
      }
      float e = __expf(sdot - m);
      sum += e; sum2 += e * e;
#pragma unroll
      for (int j = 0; j < 8; ++j) acc[j] += e * vv[kki * 8 + j];
    }
  }
  if (g > 0 && tq < Sq) {
    pm[g - 1][tq] = m; psum[g - 1][tq] = sum; psum2[g - 1][tq] = sum2;
#pragma unroll
    for (int j = 0; j < 8; ++j) pacc[g - 1][tq][j] = acc[j];
  }
  __syncthreads();
  float rowsum2 = 0.f;
  if (g == 0 && tq < Sq) {
    float mf = m;
#pragma unroll
    for (int p = 0; p < 3; ++p) mf = fmaxf(mf, pm[p][tq]);
    float f0 = __expf(m - mf);
    float f1 = __expf(pm[0][tq] - mf);
    float f2 = __expf(pm[1][tq] - mf);
    float f3 = __expf(pm[2][tq] - mf);
    float sumf = sum * f0 + psum[0][tq] * f1 + psum[1][tq] * f2 + psum[2][tq] * f3;
    float invs = 1.f / sumf;
#pragma unroll
    for (int j = 0; j < 8; ++j) {
      float a = acc[j] * f0 + pacc[0][tq][j] * f1 + pacc[1][tq][j] * f2 +
                pacc[2][tq][j] * f3;
      ctx[(size_t)(qb + b * Sq + tq) * 64 + h * 8 + j] = a * invs;
    }
    rowsum2 = (sum2 * f0 * f0 + psum2[0][tq] * f1 * f1 +
               psum2[1][tq] * f2 * f2 + psum2[2][tq] * f3 * f3) * invs * invs;
  }
  if (als != 0.f) {
    float wsum = rowsum2;
    for (int off = 32; off; off >>= 1) wsum += __shfl_down(wsum, off, 64);
    __shared__ float wred[10];
    if ((t & 63) == 0) wred[t >> 6] = wsum;
    __syncthreads();
    if (t == 0) {
      float tot = 0.f;
#pragma unroll
      for (int w = 0; w < 10; ++w) tot += wred[w];
      atomicAdd(aloss_acc, tot * als);
    }
  }
}

// ---------- channel attention, both branches (grid 64) ----------
__global__ __launch_bounds__(512) void ca_kernel(
    const float* __restrict__ ctx, const float* __restrict__ t_ca_w1,
    const float* __restrict__ t_ca_w2, int l, float* __restrict__ ca) {
  int bp = blockIdx.x;  // 0..63
  int branch = bp >> 5, b = bp & 31;
  int S = branch ? SP : SE;
  int base = branch ? ROWS_EN : 0;
  int idx = branch * 2 + l;
  const float* W1 = t_ca_w1 + idx * 512;
  const float* W2 = t_ca_w2 + idx * 512;
  int t = threadIdx.x;  // 512
  int c = t & 63, seg = t >> 6;
  float sum = 0.f, mx = -INFINITY;
  for (int s = seg; s < S; s += 8) {
    float v = ctx[(size_t)(base + b * S + s) * 64 + c];
    sum += v; mx = fmaxf(mx, v);
  }
  __shared__ float ssum[8][64], smx[8][64];
  ssum[seg][c] = sum; smx[seg][c] = mx;
  __syncthreads();
  __shared__ float avg_l[64], mx_l[64], ha[8], hm[8];
  if (t < 64) {
    float a = 0.f, m = -INFINITY;
#pragma unroll
    for (int g = 0; g < 8; ++g) { a += ssum[g][t]; m = fmaxf(m, smx[g][t]); }
    avg_l[t] = a / (float)S; mx_l[t] = m;
  }
  __syncthreads();
  if (t < 8) {
    float a = 0.f, m2 = 0.f;
    for (int i = 0; i < 64; ++i) {
      a += avg_l[i] * W1[i * 8 + t];
      m2 += mx_l[i] * W1[i * 8 + t];
    }
    ha[t] = fmaxf(a, 0.f); hm[t] = fmaxf(m2, 0.f);
  }
  __syncthreads();
  if (t < 64) {
    float o = 0.f;
#pragma unroll
    for (int j = 0; j < 8; ++j) o += (ha[j] + hm[j]) * W2[j * 64 + t];
    ca[bp * 64 + t] = 1.f / (1.f + expf(-o));
  }
}

// ---------- apply ca + spatial feat, both branches ----------
__global__ __launch_bounds__(256) void feat_kernel(
    float* __restrict__ ctx, const float* __restrict__ ca,
    float* __restrict__ fmean, float* __restrict__ fmax) {
  int row = blockIdx.x * 4 + (threadIdx.x >> 6);
  int branch, b, s, S, lrow;
  row_decode(row, branch, b, s, S, lrow);
  int c = threadIdx.x & 63;
  float v = ctx[row * 64 + c] * ca[(branch * 32 + b) * 64 + c];
  ctx[row * 64 + c] = v;
  float sum = v, mx = v;
  for (int off = 32; off; off >>= 1) {
    sum += __shfl_xor(sum, off, 64);
    mx = fmaxf(mx, __shfl_xor(mx, off, 64));
  }
  if (c == 0) { fmean[row] = sum * (1.f / 64.f); fmax[row] = mx; }
}

// ---------- fused tail: sa + out proj + LN1 + FFN + LN2, 4 rows/block ----------
__global__ __launch_bounds__(256) void tail_kernel(
    const float* __restrict__ ctx, const float* __restrict__ fmean,
    const float* __restrict__ fmax, const float* __restrict__ t_sa_w,
    const float* __restrict__ t_o_w, const float* __restrict__ t_o_b,
    const float* __restrict__ t_ln1, const float* __restrict__ t_ff1_w,
    const float* __restrict__ t_ff1_b, const float* __restrict__ t_ff2_w,
    const float* __restrict__ t_ff2_b, const float* __restrict__ t_ln2,
    int l, float* __restrict__ Xen, float* __restrict__ Xpr) {
  int t = threadIdx.x;
  int wid = t >> 6, lane = t & 63;
  int row = blockIdx.x * 4 + wid;
  int branch, b, s, S, lrow;
  row_decode(row, branch, b, s, S, lrow);
  int idx = branch * 2 + l;
  const float* sa_w = t_sa_w + idx * 14;
  float sa = 0.f;
  if (lane == 0) {
    for (int k = 0; k < 7; ++k) {
      int p = s + k - 3;
      if (p >= 0 && p < S)
        sa += fmean[row - s + p] * sa_w[k] + fmax[row - s + p] * sa_w[7 + k];
    }
    sa = 1.f / (1.f + expf(-sa));
  }
  sa = __shfl(sa, 0, 64);
  __shared__ float rowv[4][64], xr[4][64], h[4][256];
  rowv[wid][lane] = ctx[row * 64 + lane] * sa;
  __syncthreads();
  const float* o_w = t_o_w + (size_t)idx * 4096;
  float p0 = t_o_b[idx * 64 + lane], p1 = 0.f, p2 = 0.f, p3 = 0.f;
  for (int c = 0; c < 64; c += 4) {
    p0 += rowv[wid][c] * o_w[c * 64 + lane];
    p1 += rowv[wid][c + 1] * o_w[(c + 1) * 64 + lane];
    p2 += rowv[wid][c + 2] * o_w[(c + 2) * 64 + lane];
    p3 += rowv[wid][c + 3] * o_w[(c + 3) * 64 + lane];
  }
  float o = (p0 + p1) + (p2 + p3);
  float* X = branch ? Xpr : Xen;
  float r = X[lrow * 64 + lane] + o;
  float mu = r;
  for (int of = 32; of; of >>= 1) mu += __shfl_xor(mu, of, 64);
  mu *= (1.f / 64.f);
  float d = r - mu;
  float var = d * d;
  for (int of = 32; of; of >>= 1) var += __shfl_xor(var, of, 64);
  var *= (1.f / 64.f);
  const float* ln1 = t_ln1 + idx * 128;
  float x1 = d * rsqrtf(var + 1e-5f) * ln1[lane] + ln1[64 + lane];
  xr[wid][lane] = x1;
  __syncthreads();
  const float* W1 = t_ff1_w + (size_t)idx * 16384;
  float a0 = t_ff1_b[idx * 256 + t], a1 = a0, a2 = a0, a3 = a0;
  for (int c = 0; c < 64; ++c) {
    float w = W1[c * 256 + t];
    a0 += xr[0][c] * w; a1 += xr[1][c] * w; a2 += xr[2][c] * w; a3 += xr[3][c] * w;
  }
  h[0][t] = fmaxf(a0, 0.f); h[1][t] = fmaxf(a1, 0.f);
  h[2][t] = fmaxf(a2, 0.f); h[3][t] = fmaxf(a3, 0.f);
  __syncthreads();
  const float* W2 = t_ff2_w + (size_t)idx * 16384;
  float q0 = t_ff2_b[idx * 64 + lane], q1 = 0.f, q2 = 0.f, q3 = 0.f;
  for (int j = 0; j < 256; j += 4) {
    q0 += h[wid][j] * W2[j * 64 + lane];
    q1 += h[wid][j + 1] * W2[(j + 1) * 64 + lane];
    q2 += h[wid][j + 2] * W2[(j + 2) * 64 + lane];
    q3 += h[wid][j + 3] * W2[(j + 3) * 64 + lane];
  }
  float o2 = (q0 + q1) + (q2 + q3);
  float r2 = x1 + o2;
  mu = r2;
  for (int of = 32; of; of >>= 1) mu += __shfl_xor(mu, of, 64);
  mu *= (1.f / 64.f);
  d = r2 - mu;
  var = d * d;
  for (int of = 32; of; of >>= 1) var += __shfl_xor(var, of, 64);
  var *= (1.f / 64.f);
  const float* ln2 = t_ln2 + idx * 128;
  X[lrow * 64 + lane] = d * rsqrtf(var + 1e-5f) * ln2[lane] + ln2[64 + lane];
}

// ---------- cross projections: Q(en) + K,V(pr) in one launch (ILP) ----------
__global__ __launch_bounds__(256) void cross_proj_kernel(
    const float* __restrict__ Xen, const float* __restrict__ Xpr,
    const float* __restrict__ Wt, const float* __restrict__ bias,
    float* __restrict__ Q, float* __restrict__ K, float* __restrict__ V) {
  int t = threadIdx.x;
  int wid = t >> 6, oc = t & 63;
  int blk = blockIdx.x;
  __shared__ float xr[4][64];
  if (blk < ROWS_EN / 4) {
    int row = blk * 4 + wid;
    xr[wid][oc] = Xen[row * 64 + oc];
    __syncthreads();
    float p0 = bias[oc], p1 = 0.f, p2 = 0.f, p3 = 0.f;
    for (int c = 0; c < 64; c += 4) {
      p0 += xr[wid][c] * Wt[c * 64 + oc];
      p1 += xr[wid][c + 1] * Wt[(c + 1) * 64 + oc];
      p2 += xr[wid][c + 2] * Wt[(c + 2) * 64 + oc];
      p3 += xr[wid][c + 3] * Wt[(c + 3) * 64 + oc];
    }
    Q[row * 64 + oc] = (p0 + p1) + (p2 + p3);
  } else {
    int lr = (blk - ROWS_EN / 4) * 4 + wid;
    xr[wid][oc] = Xpr[lr * 64 + oc];
    __syncthreads();
    float k0 = bias[64 + oc], k1 = 0.f, v0 = bias[128 + oc], v1 = 0.f;
    for (int c = 0; c < 64; c += 2) {
      float xa = xr[wid][c], xb = xr[wid][c + 1];
      k0 += xa * Wt[4096 + c * 64 + oc];
      k1 += xb * Wt[4096 + (c + 1) * 64 + oc];
      v0 += xa * Wt[8192 + c * 64 + oc];
      v1 += xb * Wt[8192 + (c + 1) * 64 + oc];
    }
    K[(ROWS_EN + lr) * 64 + oc] = k0 + k1;
    V[(ROWS_EN + lr) * 64 + oc] = v0 + v1;
  }
}

// ---------- self QKV for en(AttEn) + pr(Xpr) in one launch (2x ILP) ----------
__global__ __launch_bounds__(256) void self_qkv_kernel(
    const float* __restrict__ inEn, const float* __restrict__ inPr,
    const float* __restrict__ Wt, const float* __restrict__ bias,
    float* __restrict__ Q, float* __restrict__ K, float* __restrict__ V) {
  int t = threadIdx.x;
  int wid = t >> 6, oc = t & 63;
  int row = blockIdx.x * 4 + wid;
  const float* in; int lrow;
  if (row < ROWS_EN) { in = inEn; lrow = row; }
  else { in = inPr; lrow = row - ROWS_EN; }
  __shared__ float xr[4][64];
  xr[wid][oc] = in[lrow * 64 + oc];
  __syncthreads();
  float q0 = bias[oc], k0 = bias[64 + oc], v0 = bias[128 + oc];
  float q1 = 0.f, k1 = 0.f, v1 = 0.f;
  for (int c = 0; c < 64; c += 2) {
    float xa = xr[wid][c], xb = xr[wid][c + 1];
    q0 += xa * Wt[c * 64 + oc];
    q1 += xb * Wt[(c + 1) * 64 + oc];
    k0 += xa * Wt[4096 + c * 64 + oc];
    k1 += xb * Wt[4096 + (c + 1) * 64 + oc];
    v0 += xa * Wt[8192 + c * 64 + oc];
    v1 += xb * Wt[8192 + (c + 1) * 64 + oc];
  }
  Q[row * 64 + oc] = q0 + q1;
  K[row * 64 + oc] = k0 + k1;
  V[row * 64 + oc] = v0 + v1;
}

// ---------- out projection, en->out0, pr->out1 (4-acc ILP) ----------
__global__ __launch_bounds__(256) void dual_proj_kernel(
    const float* __restrict__ in, const float* __restrict__ Wt,
    const float* __restrict__ bias, float* __restrict__ out0,
    float* __restrict__ out1) {
  int t = threadIdx.x;
  int wid = t >> 6, oc = t & 63;
  int row = blockIdx.x * 4 + wid;
  float* out; int lrow;
  if (row < ROWS_EN) { out = out0; lrow = row; }
  else { out = out1; lrow = row - ROWS_EN; }
  __shared__ float xr[4][64];
  xr[wid][oc] = in[row * 64 + oc];
  __syncthreads();
  float p0 = bias[oc], p1 = 0.f, p2 = 0.f, p3 = 0.f;
  for (int c = 0; c < 64; c += 4) {
    p0 += xr[wid][c] * Wt[c * 64 + oc];
    p1 += xr[wid][c + 1] * Wt[(c + 1) * 64 + oc];
    p2 += xr[wid][c + 2] * Wt[(c + 2) * 64 + oc];
    p3 += xr[wid][c + 3] * Wt[(c + 3) * 64 + oc];
  }
  out[lrow * 64 + oc] = (p0 + p1) + (p2 + p3);
}

// ---------- mean over sequence -> combined + fourier trig table ----------
__global__ __launch_bounds__(512) void mean_trig_kernel(
    const float* __restrict__ en_fin, const float* __restrict__ pr_fin,
    float* __restrict__ comb, float* __restrict__ trig) {
  int b = blockIdx.x;
  int t = threadIdx.x;
  int col = t & 127, seg = t >> 7;
  float sum = 0.f;
  if (col < 64) {
    for (int s = seg; s < SE; s += 4) sum += en_fin[(b * SE + s) * 64 + col];
  } else {
    int c = col - 64;
    for (int s = seg; s < SP; s += 4) sum += pr_fin[(b * SP + s) * 64 + c];
  }
  __shared__ float red[4][128];
  __shared__ float comb_s[128];
  red[seg][col] = sum;
  __syncthreads();
  if (t < 128) {
    float tot = red[0][t] + red[1][t] + red[2][t] + red[3][t];
    float cv = tot / (t < 64 ? (float)SE : (float)SP);
    comb_s[t] = cv;
    comb[b * 128 + t] = cv;
  }
  __syncthreads();
  for (int i = t; i < 640; i += 512) {
    int ii = i / 5, g = i - ii * 5;
    float x = comb_s[ii] * (float)(g + 1);
    trig[b * 1280 + i] = cosf(x);
    trig[b * 1280 + 640 + i] = sinf(x);
  }
}

// ---------- fourier layer 1 (pure dot over precomputed trig) ----------
__global__ __launch_bounds__(256) void fourier1_kernel(
    const float* __restrict__ trig, const float* __restrict__ wc,
    const float* __restrict__ ws, const float* __restrict__ bias,
    float* __restrict__ hidden) {
  int b = blockIdx.x;
  int t = threadIdx.x;
  int wid = t >> 6, lane = t & 63;
  int o = blockIdx.y * 4 + wid;
  if (o >= 257) return;
  const float* ct = trig + b * 1280;
  const float* st = ct + 640;
  float acc = 0.f;
  for (int i = lane; i < 640; i += 64)
    acc += ct[i] * wc[(size_t)o * 640 + i] + st[i] * ws[(size_t)o * 640 + i];
  for (int off = 32; off; off >>= 1) acc += __shfl_xor(acc, off, 64);
  if (lane == 0) hidden[b * 257 + o] = acc + bias[o];
}

// ---------- fourier layer 2 + sigmoid + aloss writeout ----------
__global__ void fourier2_kernel(const float* __restrict__ hidden,
                                const float* __restrict__ wc,
                                const float* __restrict__ ws,
                                const float* __restrict__ bias,
                                const float* __restrict__ aloss_acc,
                                float* __restrict__ out) {
  int b = blockIdx.x;
  int t = threadIdx.x;  // 320
  float acc = 0.f;
  if (t < 257) {
    float x = hidden[b * 257 + t];
#pragma unroll
    for (int g = 0; g < 5; ++g) {
      float a = x * (float)(g + 1);
      acc += cosf(a) * wc[t * 5 + g] + sinf(a) * ws[t * 5 + g];
    }
  }
  for (int off = 32; off; off >>= 1) acc += __shfl_xor(acc, off, 64);
  __shared__ float wred[5];
  if ((t & 63) == 0) wred[t >> 6] = acc;
  __syncthreads();
  if (t == 0) {
    float tot = wred[0] + wred[1] + wred[2] + wred[3] + wred[4] + bias[0];
    out[b] = 1.f / (1.f + expf(-tot));
    if (b == 0) out[4128] = aloss_acc[0];
  }
}

extern "C" void kernel_launch(void* const* d_in, const int* in_sizes, int n_in,
                              void* d_out, int out_size, void* d_ws, size_t ws_size,
                              hipStream_t stream) {
  const int* en_ids = (const int*)d_in[0];
  const int* pr_ids = (const int*)d_in[1];
  const float* emb_en = (const float*)d_in[4];
  const float* emb_pr = (const float*)d_in[5];
  const float* conv_w_en = (const float*)d_in[6];
  const float* conv_b_en = (const float*)d_in[7];
  const float* conv_w_pr = (const float*)d_in[8];
  const float* conv_b_pr = (const float*)d_in[9];
  const float* bn_en = (const float*)d_in[10];
  const float* bn_pr = (const float*)d_in[11];
  const float* t_qkv_w = (const float*)d_in[12];
  const float* t_qkv_b = (const float*)d_in[13];
  const float* t_o_w = (const float*)d_in[14];
  const float* t_o_b = (const float*)d_in[15];
  const float* t_ca_w1 = (const float*)d_in[16];
  const float* t_ca_w2 = (const float*)d_in[17];
  const float* t_sa_w = (const float*)d_in[18];
  const float* t_ff1_w = (const float*)d_in[19];
  const float* t_ff1_b = (const float*)d_in[20];
  const float* t_ff2_w = (const float*)d_in[21];
  const float* t_ff2_b = (const float*)d_in[22];
  const float* t_ln1 = (const float*)d_in[23];
  const float* t_ln2 = (const float*)d_in[24];
  const float* cross_in_w = (const float*)d_in[25];
  const float* cross_in_b = (const float*)d_in[26];
  const float* cross_out_w = (const float*)d_in[27];
  const float* cross_out_b = (const float*)d_in[28];
  const float* self_in_w = (const float*)d_in[29];
  const float* self_in_b = (const float*)d_in[30];
  const float* self_out_w = (const float*)d_in[31];
  const float* self_out_b = (const float*)d_in[32];
  const float* fk1_c = (const float*)d_in[33];
  const float* fk1_s = (const float*)d_in[34];
  const float* fk1_b = (const float*)d_in[35];
  const float* fk2_c = (const float*)d_in[36];
  const float* fk2_s = (const float*)d_in[37];
  const float* fk2_b = (const float*)d_in[38];

  float* out = (float*)d_out;
  float* ws = (float*)d_ws;
  size_t off = 0;
  float* Cen = ws + off;  off += (size_t)4097 * 576;
  float* Cpr = ws + off;  off += (size_t)4097 * 576;
  float* W2en = ws + off; off += 73728;
  float* W2pr = ws + off; off += 73728;
  float* Wt = ws + off;   off += 8 * 4096;
  float* Xen = ws + off;  off += (size_t)ROWS_EN * 64;
  float* Xpr = ws + off;  off += (size_t)ROWS_PR * 64;
  float* Qb = ws + off;   off += (size_t)ROWS_ALL * 64;
  float* Kb = ws + off;   off += (size_t)ROWS_ALL * 64;
  float* Vb = ws + off;   off += (size_t)ROWS_ALL * 64;
  float* Ctx = ws + off;  off += (size_t)ROWS_ALL * 64;
  float* AttEn = ws + off; off += (size_t)ROWS_EN * 64;
  float* PrFin = ws + off; off += (size_t)ROWS_PR * 64;
  float* Fm = ws + off;   off += ROWS_ALL;
  float* Fx = ws + off;   off += ROWS_ALL;
  float* CaB = ws + off;  off += 2 * BB * 64;
  float* Hid = ws + off;  off += BB * 257;
  float* Trig = ws + off; off += (size_t)BB * 1280;
  float* Al = ws + off;   off += 8;

  const float als_en = 1.f / ((float)BB * 8.f * (float)SE * (float)SE);
  const float als_pr = 1.f / ((float)BB * 8.f * (float)SP * (float)SP);

  // setup: transposes + Al zero
  prep_kernel<<<584, 256, 0, stream>>>(conv_w_en, conv_w_pr, cross_in_w,
                                       cross_out_w, self_in_w, self_out_w,
                                       W2en, W2pr, Wt, Al);
  // frontend (both branches)
  conv_table_kernel<<<1026, 192, 0, stream>>>(emb_en, emb_pr, W2en, W2pr, Cen, Cpr);
  frontend_kernel<<<ROWS_ALL / 4, 256, 0, stream>>>(en_ids, pr_ids, Cen, Cpr,
                                                    conv_b_en, conv_b_pr, bn_en,
                                                    bn_pr, Xen, Xpr);

  // transformer layers (both branches per launch)
  for (int l = 0; l < 2; ++l) {
    qkv_rope_kernel<<<ROWS_ALL / 4, 256, 0, stream>>>(Xen, Xpr, t_qkv_w,
                                                      t_qkv_b, l, Qb, Kb, Vb);
    attn_kernel<<<512, 640, 0, stream>>>(Qb, Kb, Vb, Ctx,
                                         256, SE, SE, 0, 0, als_en,
                                         SP, SP, ROWS_EN, ROWS_EN, als_pr, Al);
    ca_kernel<<<64, 512, 0, stream>>>(Ctx, t_ca_w1, t_ca_w2, l, CaB);
    feat_kernel<<<ROWS_ALL / 4, 256, 0, stream>>>(Ctx, CaB, Fm, Fx);
    tail_kernel<<<ROWS_ALL / 4, 256, 0, stream>>>(
        Ctx, Fm, Fx, t_sa_w, t_o_w, t_o_b, t_ln1, t_ff1_w, t_ff1_b,
        t_ff2_w, t_ff2_b, t_ln2, l, Xen, Xpr);
  }

  // cross attention: en_att = mha(en, pr, pr)
  cross_proj_kernel<<<ROWS_ALL / 4, 256, 0, stream>>>(Xen, Xpr, Wt,
                                                      cross_in_b, Qb, Kb, Vb);
  attn_kernel<<<256, 640, 0, stream>>>(Qb, Kb, Vb, Ctx,
                                       256, SE, SP, 0, ROWS_EN, 0.f,
                                       0, 0, 0, 0, 0.f, Al);
  dual_proj_kernel<<<ROWS_EN / 4, 256, 0, stream>>>(Ctx, Wt + 3 * 4096,
                                                    cross_out_b, AttEn, AttEn);

  // self attention: en(AttEn) and pr(Xpr) merged
  self_qkv_kernel<<<ROWS_ALL / 4, 256, 0, stream>>>(AttEn, Xpr, Wt + 4 * 4096,
                                                    self_in_b, Qb, Kb, Vb);
  attn_kernel<<<512, 640, 0, stream>>>(Qb, Kb, Vb, Ctx,
                                       256, SE, SE, 0, 0, 0.f,
                                       SP, SP, ROWS_EN, ROWS_EN, 0.f, Al);
  dual_proj_kernel<<<ROWS_ALL / 4, 256, 0, stream>>>(Ctx, Wt + 7 * 4096,
                                                     self_out_b, Xen, PrFin);

  // combined + fourier head
  mean_trig_kernel<<<BB, 512, 0, stream>>>(Xen, PrFin, out + 32, Trig);
  fourier1_kernel<<<dim3(BB, 65), 256, 0, stream>>>(Trig, fk1_c, fk1_s,
                                                    fk1_b, Hid);
  fourier2_kernel<<<BB, 320, 0, stream>>>(Hid, fk2_c, fk2_s, fk2_b, Al, out);
}